// Round 10
// baseline (263.491 us; speedup 1.0000x reference)
//
#include <hip/hip_runtime.h>

// GAT forward (2x GATConv + GlobalAttention pool) for MI355X.
// R27 = R26 (best, 231.7us) + cross-node h8 prefetch in agg1_gemm2 (R26's
// intra-node overlap extended): all 4 nodes' csr/cnt/adst scalars loaded at
// kernel start; two-slot register buffer dbuf[2][8] rotates so node nl+1's
// h8 gathers are issued BEFORE node nl's weight+accumulate phase (a full
// node-processing time to land, not just the weight phase). Full unroll ->
// static dbuf indexing (no scratch). aggregate_kernel keeps R26 agg_node.
// 7 launches.

constexpr int NN = 50000;          // nodes
constexpr int EE = 800000;         // edges (without self loops)
constexpr int NG = 64;             // graphs
constexpr float NEG = 0.2f;       // leaky relu slope
constexpr int MT = NN / 16;        // 3125 m-tiles (NN % 16 == 0)
constexpr int SLOTS = 64;          // CSR slots per node; P(deg>64) ~ 0 (Poisson(16)+1)
constexpr int CH = 16;             // pool chunks per graph
constexpr int GB = (MT + 3) / 4;   // gemm blocks (wave per m-tile, 4 waves/block)

constexpr int EB_EDGES = 4096;                     // edges per hist block
constexpr int EBN = (EE + EB_EDGES - 1) / EB_EDGES; // 196 hist blocks
constexpr int NBKT = (NN + 255) / 256;             // 196 coarse buckets (dst>>8)
constexpr int CAP = 48;            // bin capacity; Poisson(20.9), P(>48)*bins ~ 0.1
constexpr int OVFCAP = 8192;       // overflow fallback list

static_assert(NN % 16 == 0, "fused block = 16 nodes");

using bf16x8 = __attribute__((ext_vector_type(8))) __bf16;
using f32x4  = __attribute__((ext_vector_type(4))) float;
using f32x2  = __attribute__((ext_vector_type(2))) float;

__device__ __forceinline__ float wred(float v) {
#pragma unroll
  for (int o = 32; o; o >>= 1) v += __shfl_down(v, o);
  return v;
}
__device__ __forceinline__ float sigmoidf(float v) { return 1.f / (1.f + __expf(-v)); }
__device__ __forceinline__ float lrelu(float v) { return fmaxf(v, NEG * v); }
__device__ __forceinline__ unsigned short f2b(float f) {
  union { float f; unsigned u; } v; v.f = f;
  unsigned r = v.u + 0x7fff + ((v.u >> 16) & 1);
  return (unsigned short)(r >> 16);
}
__device__ __forceinline__ float b2f(unsigned short b) {
  union { unsigned u; float f; } v; v.u = ((unsigned)b) << 16;
  return v.f;
}

// ------- prep: pack W1/W2/gateW + graph bounds + zero ovf counter ---------------
__global__ void prep_kernel(const float* __restrict__ W1, const float* __restrict__ W2,
                            const float* __restrict__ gw1, const float* __restrict__ gamma,
                            const int* __restrict__ batch,
                            unsigned short* __restrict__ W1b, unsigned short* __restrict__ W2b,
                            unsigned short* __restrict__ Bg, int* __restrict__ goffs,
                            int* __restrict__ ovf_cnt) {
  int b = blockIdx.x;
  if (b < 128) {  // W1 pack: K=128, KC=4, N=256
    int idx = b * 256 + threadIdx.x;
    int j = idx & 7, lane = (idx >> 3) & 63, rest = idx >> 9;
    int kc = rest & 3, ntile = rest >> 2;
    W1b[idx] = f2b(W1[(kc * 32 + (lane >> 4) * 8 + j) * 256 + ntile * 16 + (lane & 15)]);
    return;
  }
  if (b < 192) {  // W2 pack: K=64, KC=2, N=256
    int idx = (b - 128) * 256 + threadIdx.x;
    int j = idx & 7, lane = (idx >> 3) & 63, rest = idx >> 9;
    int kc = rest & 1, ntile = rest >> 1;
    W2b[idx] = f2b(W2[(kc * 32 + (lane >> 4) * 8 + j) * 256 + ntile * 16 + (lane & 15)]);
    return;
  }
  if (b < 208) {  // gate W pack: K=64, KC=2, N=64, BN scale folded
    int idx = (b - 192) * 256 + threadIdx.x;  // 0..4095
    int j = idx & 7, lane = (idx >> 3) & 63, rest = idx >> 9;
    int kc = rest & 1, nt = rest >> 1;
    int k = kc * 32 + (lane >> 4) * 8 + j;
    int n = nt * 16 + (lane & 15);
    Bg[idx] = f2b(gw1[k * 64 + n] * gamma[n] * rsqrtf(1.f + 1e-5f));
    return;
  }
  // graph bounds (sorted batch, binary search) + ovf counter zero
  if (threadIdx.x == 0) *ovf_cnt = 0;
  int g = threadIdx.x;
  if (g <= NG) {
    int lo = 0, hi = NN;
    while (lo < hi) {
      int mid = (lo + hi) >> 1;
      if (batch[mid] < g) lo = mid + 1; else hi = mid;
    }
    goffs[g] = lo;
  }
}

// ------- MFMA GEMM body: A in regs, B in LDS, fused attn, TRANSPOSED fp8 C ------
template <int KC>
__device__ __forceinline__ void gemm_body(int mt, int lane, const bf16x8* av,
                                          const unsigned short* Bp,  // LDS
                                          unsigned char* __restrict__ C8,
                                          const float* __restrict__ att_s,
                                          const float* __restrict__ att_d,
                                          float* __restrict__ asrc,
                                          float* __restrict__ adst) {
  int m0 = mt * 16;
  int q = lane >> 4, r = lane & 15;
  f32x4 acc[16] = {};
#pragma unroll
  for (int kc = 0; kc < KC; ++kc) {
#pragma unroll
    for (int nt = 0; nt < 16; ++nt) {
      bf16x8 b = *(const bf16x8*)&Bp[(((unsigned)nt * KC + kc) * 64 + lane) * 8];
      acc[nt] = __builtin_amdgcn_mfma_f32_16x16x32_bf16(av[kc], b, acc[nt], 0, 0, 0);
    }
  }
  // transposed C8 store: byte p = r*16 + nt  (true channel c = nt*16 + r)
#pragma unroll
  for (int reg = 0; reg < 4; ++reg) {
    unsigned row = m0 + q * 4 + reg;
    uint4 pk;
    int w;
    w = __builtin_amdgcn_cvt_pk_fp8_f32(acc[0][reg], acc[1][reg], 0, false);
    w = __builtin_amdgcn_cvt_pk_fp8_f32(acc[2][reg], acc[3][reg], w, true);
    pk.x = (unsigned)w;
    w = __builtin_amdgcn_cvt_pk_fp8_f32(acc[4][reg], acc[5][reg], 0, false);
    w = __builtin_amdgcn_cvt_pk_fp8_f32(acc[6][reg], acc[7][reg], w, true);
    pk.y = (unsigned)w;
    w = __builtin_amdgcn_cvt_pk_fp8_f32(acc[8][reg], acc[9][reg], 0, false);
    w = __builtin_amdgcn_cvt_pk_fp8_f32(acc[10][reg], acc[11][reg], w, true);
    pk.z = (unsigned)w;
    w = __builtin_amdgcn_cvt_pk_fp8_f32(acc[12][reg], acc[13][reg], 0, false);
    w = __builtin_amdgcn_cvt_pk_fp8_f32(acc[14][reg], acc[15][reg], w, true);
    pk.w = (unsigned)w;
    *(uint4*)(C8 + (size_t)row * 256 + (unsigned)r * 16) = pk;
  }
  // fused attention dots (true-channel order)
  float ps[4][4] = {}, pd[4][4] = {};
#pragma unroll
  for (int head = 0; head < 4; ++head) {
#pragma unroll
    for (int i = 0; i < 4; ++i) {
      float sv = att_s[head * 64 + i * 16 + r];
      float dv = att_d[head * 64 + i * 16 + r];
#pragma unroll
      for (int reg = 0; reg < 4; ++reg) {
        ps[head][reg] += acc[head * 4 + i][reg] * sv;
        pd[head][reg] += acc[head * 4 + i][reg] * dv;
      }
    }
  }
#pragma unroll
  for (int head = 0; head < 4; ++head)
#pragma unroll
    for (int reg = 0; reg < 4; ++reg)
#pragma unroll
      for (int o = 1; o < 16; o <<= 1) {
        ps[head][reg] += __shfl_xor(ps[head][reg], o);
        pd[head][reg] += __shfl_xor(pd[head][reg], o);
      }
  if (r == 0) {
#pragma unroll
    for (int reg = 0; reg < 4; ++reg) {
      int row = m0 + q * 4 + reg;
#pragma unroll
      for (int head = 0; head < 4; ++head) {
        asrc[row * 4 + head] = ps[head][reg];
        adst[row * 4 + head] = pd[head][reg];
      }
    }
  }
}

// ------- GEMM1 (LDS-staged B) + atomic-free bucket-histogram pass A -------------
__global__ void gemm1_build_kernel(const float* __restrict__ x,
                                   const unsigned short* __restrict__ W1b,
                                   unsigned char* __restrict__ C8,
                                   const float* __restrict__ att_s,
                                   const float* __restrict__ att_d,
                                   float* __restrict__ asrc, float* __restrict__ adst,
                                   const int* __restrict__ ei,
                                   unsigned* __restrict__ bins,
                                   int* __restrict__ binCnt,
                                   int* __restrict__ ovf_cnt,
                                   unsigned* __restrict__ ovf) {
  __shared__ union {
    unsigned short B[128 * 256];   // 64 KB staged W1b
    int hist[NBKT];
  } smem;
  int b = blockIdx.x;
  if (b < GB) {
    int wave = threadIdx.x >> 6, lane = threadIdx.x & 63;
    int mt0 = b * 4 + wave;
    int mt = min(mt0, MT - 1);      // tail waves load safe addr, exit after barrier
    int q = lane >> 4, r = lane & 15;
    // stage B (all 256 threads; 16 x uint4 each)
#pragma unroll
    for (int it = 0; it < 16; ++it)
      ((uint4*)smem.B)[it * 256 + threadIdx.x] = ((const uint4*)W1b)[it * 256 + threadIdx.x];
    // hoisted A load + bf16 convert (overlaps staging; barrier drains all)
    bf16x8 av[4];
    {
      const float* Arow = x + (size_t)(mt * 16 + r) * 128 + q * 8;
      float4 f0[4], f1[4];
#pragma unroll
      for (int kc = 0; kc < 4; ++kc) {
        f0[kc] = *(const float4*)(Arow + kc * 32);
        f1[kc] = *(const float4*)(Arow + kc * 32 + 4);
      }
#pragma unroll
      for (int kc = 0; kc < 4; ++kc) {
        union { bf16x8 v; unsigned short s[8]; } u;
        u.s[0] = f2b(f0[kc].x); u.s[1] = f2b(f0[kc].y);
        u.s[2] = f2b(f0[kc].z); u.s[3] = f2b(f0[kc].w);
        u.s[4] = f2b(f1[kc].x); u.s[5] = f2b(f1[kc].y);
        u.s[6] = f2b(f1[kc].z); u.s[7] = f2b(f1[kc].w);
        av[kc] = u.v;
      }
    }
    __syncthreads();
    if (mt0 >= MT) return;
    gemm_body<4>(mt, lane, av, smem.B, C8, att_s, att_d, asrc, adst);
    return;
  }
  // pass A: per-block LDS histogram over coarse buckets, LDS ranks, bin scatter
  int hb = b - GB;
  for (int t = threadIdx.x; t < NBKT; t += 256) smem.hist[t] = 0;
  __syncthreads();
  int e0 = hb * EB_EDGES + threadIdx.x * 16;
#pragma unroll
  for (int k4 = 0; k4 < 4; ++k4) {
    int e = e0 + k4 * 4;
    if (e >= EE) break;
    int4 s4 = *(const int4*)&ei[e];
    int4 d4 = *(const int4*)&ei[EE + e];
    int ss[4] = {s4.x, s4.y, s4.z, s4.w};
    int dd[4] = {d4.x, d4.y, d4.z, d4.w};
#pragma unroll
    for (int u = 0; u < 4; ++u) {
      if (e + u >= EE) break;
      int src = ss[u], dst = dd[u];
      int bkt = dst >> 8;
      int rr = atomicAdd(&smem.hist[bkt], 1);   // LDS atomic — stays in the CU
      if (rr < CAP) {
        bins[((unsigned)hb * NBKT + bkt) * CAP + rr] =
            (unsigned)src | ((unsigned)(dst & 255) << 16);
      } else {  // statistically ~never; bulletproof fallback
        int o = atomicAdd(ovf_cnt, 1);
        if (o < OVFCAP) ovf[o] = (unsigned)src | ((unsigned)dst << 16);
      }
    }
  }
  __syncthreads();
  for (int t = threadIdx.x; t < NBKT; t += 256) binCnt[hb * NBKT + t] = smem.hist[t];
}

// ------- pass C: per-bucket CSR finalization (plain stores, LDS ranks) ----------
__global__ __launch_bounds__(1024) void csr_build_kernel(
    const unsigned* __restrict__ bins, const int* __restrict__ binCnt,
    const int* __restrict__ ovf_cnt, const unsigned* __restrict__ ovf,
    unsigned short* __restrict__ csr16, int* __restrict__ cnt) {
  int b = blockIdx.x;                 // bucket = nodes [b*256, b*256+256)
  __shared__ int hist[256];
  int t = threadIdx.x;
  int node0 = b << 8;
  if (t < 256) {
    hist[t] = 1;                      // slot 0 reserved for the self loop
    int node = node0 + t;
    if (node < NN) csr16[(unsigned)node * SLOTS] = (unsigned short)node;
  }
  __syncthreads();
  int wave = t >> 6, lane = t & 63;
  for (int i = wave; i < EBN; i += 16) {
    int c = binCnt[i * NBKT + b];
    if (c > CAP) c = CAP;
    for (int base = 0; base < c; base += 64) {
      int j = base + lane;
      if (j < c) {
        unsigned p = bins[((unsigned)i * NBKT + b) * CAP + j];
        int dl = p >> 16, src = p & 0xffff;
        int r = atomicAdd(&hist[dl], 1);
        if (r < SLOTS) csr16[(unsigned)(node0 + dl) * SLOTS + r] = (unsigned short)src;
      }
    }
  }
  __syncthreads();
  int oc = *ovf_cnt;
  if (oc > OVFCAP) oc = OVFCAP;
  for (int j = t; j < oc; j += 1024) {
    unsigned p = ovf[j];
    int dst = (int)(p >> 16);
    if ((dst >> 8) == b) {
      int r = atomicAdd(&hist[dst & 255], 1);
      if (r < SLOTS) csr16[(unsigned)dst * SLOTS + r] = (unsigned short)(p & 0xffff);
    }
  }
  __syncthreads();
  if (t < 256) {
    int node = node0 + t;
    if (node < NN) cnt[node] = hist[t];
  }
}

// ------- accumulate macro shared by both aggregate paths ------------------------
#define ACC4(d, wA, wB, wC, wD)                                              \
  {                                                                          \
    a[0] += __builtin_amdgcn_cvt_pk_f32_fp8((d).x, false) * (wA);            \
    a[1] += __builtin_amdgcn_cvt_pk_f32_fp8((d).x, true) * (wA);             \
    a[2] += __builtin_amdgcn_cvt_pk_f32_fp8((d).y, false) * (wB);            \
    a[3] += __builtin_amdgcn_cvt_pk_f32_fp8((d).y, true) * (wB);             \
    a[4] += __builtin_amdgcn_cvt_pk_f32_fp8((d).z, false) * (wC);            \
    a[5] += __builtin_amdgcn_cvt_pk_f32_fp8((d).z, true) * (wC);             \
    a[6] += __builtin_amdgcn_cvt_pk_f32_fp8((d).w, false) * (wD);            \
    a[7] += __builtin_amdgcn_cvt_pk_f32_fp8((d).w, true) * (wD);             \
  }

// ------- aggregate core for ONE node on ONE wave (R26 hoisted gathers) ----------
__device__ __forceinline__ float agg_node(int node, int lane,
                                          float* __restrict__ wlds,   // [256] per wave
                                          float* __restrict__ redw,   // [1056] per wave
                                          const unsigned char* __restrict__ h8,
                                          const float* __restrict__ asrc,
                                          const float* __restrict__ adst,
                                          const int* __restrict__ cnt,
                                          const unsigned short* __restrict__ csr_src) {
  int q4 = lane >> 4, r16 = lane & 15, hgrp = q4;
  int deg = min(cnt[node], SLOTS);
  float adh = adst[node * 4 + hgrp];
  int src_all = csr_src[(unsigned)node * SLOTS + lane];  // coalesced 128B load
  int dm1 = deg - 1;                                     // deg >= 1 (self loop)
  const unsigned char* hp = h8 + (unsigned)r16 * 16;
  uint4 d0, d1, d2, d3, d4, d5, d6, d7;
  {
    int s0 = __shfl(src_all, min(q4, dm1));
    int s1 = __shfl(src_all, min(q4 + 4, dm1));
    int s2 = __shfl(src_all, min(q4 + 8, dm1));
    int s3 = __shfl(src_all, min(q4 + 12, dm1));
    d0 = *(const uint4*)(hp + ((unsigned)s0 << 8));
    d1 = *(const uint4*)(hp + ((unsigned)s1 << 8));
    d2 = *(const uint4*)(hp + ((unsigned)s2 << 8));
    d3 = *(const uint4*)(hp + ((unsigned)s3 << 8));
  }
  bool haveQ1 = deg > 16;                               // wave-uniform
  if (haveQ1) {
    int s4 = __shfl(src_all, min(q4 + 16, dm1));
    int s5 = __shfl(src_all, min(q4 + 20, dm1));
    int s6 = __shfl(src_all, min(q4 + 24, dm1));
    int s7 = __shfl(src_all, min(q4 + 28, dm1));
    d4 = *(const uint4*)(hp + ((unsigned)s4 << 8));
    d5 = *(const uint4*)(hp + ((unsigned)s5 << 8));
    d6 = *(const uint4*)(hp + ((unsigned)s6 << 8));
    d7 = *(const uint4*)(hp + ((unsigned)s7 << 8));
  }
  float den = 0.f;
#pragma unroll
  for (int i = 0; i < 4; ++i) {
    int slot = i * 16 + r16;
    float w = 0.f;
    if (i * 16 < deg) {                          // wave-uniform skip (deg~17)
      int s = __shfl(src_all, slot);
      bool valid = slot < deg;
      float xv = asrc[(unsigned)(valid ? s : 0) * 4 + hgrp];
      w = valid ? __expf(lrelu(xv + adh)) : 0.f;
    }
    wlds[slot * 4 + hgrp] = w;                   // ALWAYS written (0 if invalid)
    den += w;
  }
#pragma unroll
  for (int o = 1; o < 16; o <<= 1) den += __shfl_xor(den, o);  // den per head hgrp
  __builtin_amdgcn_wave_barrier();               // keep write->read order (intra-wave)

  f32x2 a[8] = {};
  {
    f32x4 w0 = *(const f32x4*)&wlds[(unsigned)q4 * 4];
    f32x4 w1 = *(const f32x4*)&wlds[(unsigned)(q4 + 4) * 4];
    f32x4 w2 = *(const f32x4*)&wlds[(unsigned)(q4 + 8) * 4];
    f32x4 w3 = *(const f32x4*)&wlds[(unsigned)(q4 + 12) * 4];
    ACC4(d0, w0[0], w0[1], w0[2], w0[3]);
    ACC4(d1, w1[0], w1[1], w1[2], w1[3]);
    ACC4(d2, w2[0], w2[1], w2[2], w2[3]);
    ACC4(d3, w3[0], w3[1], w3[2], w3[3]);
  }
  if (haveQ1) {
    f32x4 w0 = *(const f32x4*)&wlds[(unsigned)(q4 + 16) * 4];
    f32x4 w1 = *(const f32x4*)&wlds[(unsigned)(q4 + 20) * 4];
    f32x4 w2 = *(const f32x4*)&wlds[(unsigned)(q4 + 24) * 4];
    f32x4 w3 = *(const f32x4*)&wlds[(unsigned)(q4 + 28) * 4];
    ACC4(d4, w0[0], w0[1], w0[2], w0[3]);
    ACC4(d5, w1[0], w1[1], w1[2], w1[3]);
    ACC4(d6, w2[0], w2[1], w2[2], w2[3]);
    ACC4(d7, w3[0], w3[1], w3[2], w3[3]);
  }
  // quarters 2-3 (deg > 32, rare): late-load path
  int e = 32;
#pragma unroll
  for (int i = 2; i < 4; ++i) {
    if (e >= deg) break;
    int bound = min(deg, (i + 1) * 16);
    if (bound - e == 16) {
      int eq = e + q4;
      int s0 = __shfl(src_all, eq);
      int s1 = __shfl(src_all, eq + 4);
      int s2 = __shfl(src_all, eq + 8);
      int s3 = __shfl(src_all, eq + 12);
      f32x4 w0 = *(const f32x4*)&wlds[(unsigned)eq * 4];
      f32x4 w1 = *(const f32x4*)&wlds[(unsigned)(eq + 4) * 4];
      f32x4 w2 = *(const f32x4*)&wlds[(unsigned)(eq + 8) * 4];
      f32x4 w3 = *(const f32x4*)&wlds[(unsigned)(eq + 12) * 4];
      uint4 e0 = *(const uint4*)(hp + ((unsigned)s0 << 8));
      uint4 e1 = *(const uint4*)(hp + ((unsigned)s1 << 8));
      uint4 e2 = *(const uint4*)(hp + ((unsigned)s2 << 8));
      uint4 e3 = *(const uint4*)(hp + ((unsigned)s3 << 8));
      ACC4(e0, w0[0], w0[1], w0[2], w0[3]);
      ACC4(e1, w1[0], w1[1], w1[2], w1[3]);
      ACC4(e2, w2[0], w2[1], w2[2], w2[3]);
      ACC4(e3, w3[0], w3[1], w3[2], w3[3]);
      e += 16;
    } else {
      for (; e < bound; e += 4) {
        int gg = min(4, bound - e);
        int q4e = min(q4, gg - 1);
        int su = __shfl(src_all, e + q4e);
        f32x4 wv = *(const f32x4*)&wlds[(unsigned)(e + q4e) * 4];
        if (q4 >= gg) { wv[0] = 0.f; wv[1] = 0.f; wv[2] = 0.f; wv[3] = 0.f; }
        uint4 d = *(const uint4*)(hp + ((unsigned)su << 8));
        ACC4(d, wv[0], wv[1], wv[2], wv[3]);
      }
    }
  }
  // per-head normalize (0.25 = head-mean folded), then LDS transpose
  float dh0 = __shfl(den, 0), dh1 = __shfl(den, 16);
  float dh2 = __shfl(den, 32), dh3 = __shfl(den, 48);
  float i0 = 0.25f / (dh0 + 1e-16f), i1 = 0.25f / (dh1 + 1e-16f);
  float i2 = 0.25f / (dh2 + 1e-16f), i3 = 0.25f / (dh3 + 1e-16f);
  f32x4 v0 = {a[0].x * i0, a[0].y * i0, a[1].x * i0, a[1].y * i0};
  f32x4 v1 = {a[2].x * i1, a[2].y * i1, a[3].x * i1, a[3].y * i1};
  f32x4 v2 = {a[4].x * i2, a[4].y * i2, a[5].x * i2, a[5].y * i2};
  f32x4 v3 = {a[6].x * i3, a[6].y * i3, a[7].x * i3, a[7].y * i3};
  float* wb2 = &redw[(unsigned)lane * 16 + (lane & 7) * 4];
  *(f32x4*)(wb2 + 0) = v0;
  *(f32x4*)(wb2 + 4) = v1;
  *(f32x4*)(wb2 + 8) = v2;
  *(f32x4*)(wb2 + 12) = v3;
  __builtin_amdgcn_wave_barrier();
  int base = (lane & 15) * 16 + (lane & 7) * 4 + (lane >> 4);
  float s = 0.f;
#pragma unroll
  for (int q = 0; q < 4; ++q)
#pragma unroll
    for (int h = 0; h < 4; ++h)
      s += redw[q * 256 + base + 4 * h];
  return s;
}

// ------- FUSED aggregate1 + gemm2 + attn2: block = 16 nodes, x-node prefetch ----
__global__ void agg1_gemm2_kernel(const unsigned char* __restrict__ h8,
                                  const float* __restrict__ asrc1,
                                  const float* __restrict__ adst1,
                                  const int* __restrict__ cnt,
                                  const unsigned short* __restrict__ csr_src,
                                  const float* __restrict__ b1,
                                  const unsigned short* __restrict__ W2b,
                                  const float* __restrict__ as2,
                                  const float* __restrict__ ad2,
                                  unsigned char* __restrict__ h8b,
                                  float* __restrict__ asrc2,
                                  float* __restrict__ adst2) {
  int wv = threadIdx.x >> 6, lane = threadIdx.x & 63;
  int q4 = lane >> 4, r16 = lane & 15, hgrp = q4;
  __shared__ float wtab[4][256];
  __shared__ union { float red[4][1056]; unsigned ctile[16 * 64]; } sm;
  __shared__ unsigned short A16[16][72];     // out1 tile, +8 pad per row
  const unsigned char* hp = h8 + (unsigned)r16 * 16;
  float* wlds = wtab[wv];
  float* redw = sm.red[wv];

  // ---- preload all 4 nodes' scalars (independent; overlapping chains) ----
  int node0 = blockIdx.x * 16 + wv * 4;
  int srcA[4], degA[4];
  float adhA[4];
#pragma unroll
  for (int nl = 0; nl < 4; ++nl) {
    srcA[nl] = csr_src[(unsigned)(node0 + nl) * SLOTS + lane];
    degA[nl] = min(cnt[node0 + nl], SLOTS);
    adhA[nl] = adst1[(node0 + nl) * 4 + hgrp];
  }
#define PREFETCH_H8(sa, degv, dd, q1)                                        \
  {                                                                          \
    int dm1 = (degv) - 1;                                                    \
    int s0 = __shfl(sa, min(q4, dm1));                                       \
    int s1 = __shfl(sa, min(q4 + 4, dm1));                                   \
    int s2 = __shfl(sa, min(q4 + 8, dm1));                                   \
    int s3 = __shfl(sa, min(q4 + 12, dm1));                                  \
    dd[0] = *(const uint4*)(hp + ((unsigned)s0 << 8));                       \
    dd[1] = *(const uint4*)(hp + ((unsigned)s1 << 8));                       \
    dd[2] = *(const uint4*)(hp + ((unsigned)s2 << 8));                       \
    dd[3] = *(const uint4*)(hp + ((unsigned)s3 << 8));                       \
    q1 = (degv) > 16;                                                        \
    if (q1) {                                                                \
      int s4 = __shfl(sa, min(q4 + 16, dm1));                                \
      int s5 = __shfl(sa, min(q4 + 20, dm1));                                \
      int s6 = __shfl(sa, min(q4 + 24, dm1));                                \
      int s7 = __shfl(sa, min(q4 + 28, dm1));                                \
      dd[4] = *(const uint4*)(hp + ((unsigned)s4 << 8));                     \
      dd[5] = *(const uint4*)(hp + ((unsigned)s5 << 8));                     \
      dd[6] = *(const uint4*)(hp + ((unsigned)s6 << 8));                     \
      dd[7] = *(const uint4*)(hp + ((unsigned)s7 << 8));                     \
    }                                                                        \
  }
  uint4 dbuf[2][8];
  bool q1buf[2];
  PREFETCH_H8(srcA[0], degA[0], dbuf[0], q1buf[0]);
#pragma unroll
  for (int nl = 0; nl < 4; ++nl) {
    const int cur = nl & 1, nxt = cur ^ 1;
    if (nl < 3) PREFETCH_H8(srcA[nl + 1], degA[nl + 1], dbuf[nxt], q1buf[nxt]);
    int src_all = srcA[nl], deg = degA[nl];
    float adh = adhA[nl];
    // ---- weight phase (prefetched gathers in flight) ----
    float den = 0.f;
#pragma unroll
    for (int i = 0; i < 4; ++i) {
      int slot = i * 16 + r16;
      float w = 0.f;
      if (i * 16 < deg) {
        int s = __shfl(src_all, slot);
        bool valid = slot < deg;
        float xv = asrc1[(unsigned)(valid ? s : 0) * 4 + hgrp];
        w = valid ? __expf(lrelu(xv + adh)) : 0.f;
      }
      wlds[slot * 4 + hgrp] = w;
      den += w;
    }
#pragma unroll
    for (int o = 1; o < 16; o <<= 1) den += __shfl_xor(den, o);
    __builtin_amdgcn_wave_barrier();
    // ---- accumulate with prefetched rows ----
    f32x2 a[8] = {};
    {
      f32x4 w0 = *(const f32x4*)&wlds[(unsigned)q4 * 4];
      f32x4 w1 = *(const f32x4*)&wlds[(unsigned)(q4 + 4) * 4];
      f32x4 w2 = *(const f32x4*)&wlds[(unsigned)(q4 + 8) * 4];
      f32x4 w3 = *(const f32x4*)&wlds[(unsigned)(q4 + 12) * 4];
      ACC4(dbuf[cur][0], w0[0], w0[1], w0[2], w0[3]);
      ACC4(dbuf[cur][1], w1[0], w1[1], w1[2], w1[3]);
      ACC4(dbuf[cur][2], w2[0], w2[1], w2[2], w2[3]);
      ACC4(dbuf[cur][3], w3[0], w3[1], w3[2], w3[3]);
    }
    if (q1buf[cur]) {
      f32x4 w0 = *(const f32x4*)&wlds[(unsigned)(q4 + 16) * 4];
      f32x4 w1 = *(const f32x4*)&wlds[(unsigned)(q4 + 20) * 4];
      f32x4 w2 = *(const f32x4*)&wlds[(unsigned)(q4 + 24) * 4];
      f32x4 w3 = *(const f32x4*)&wlds[(unsigned)(q4 + 28) * 4];
      ACC4(dbuf[cur][4], w0[0], w0[1], w0[2], w0[3]);
      ACC4(dbuf[cur][5], w1[0], w1[1], w1[2], w1[3]);
      ACC4(dbuf[cur][6], w2[0], w2[1], w2[2], w2[3]);
      ACC4(dbuf[cur][7], w3[0], w3[1], w3[2], w3[3]);
    }
    // quarters 2-3 (deg > 32, rare): late-load path
    int e = 32;
#pragma unroll
    for (int i = 2; i < 4; ++i) {
      if (e >= deg) break;
      int bound = min(deg, (i + 1) * 16);
      if (bound - e == 16) {
        int eq = e + q4;
        int s0 = __shfl(src_all, eq);
        int s1 = __shfl(src_all, eq + 4);
        int s2 = __shfl(src_all, eq + 8);
        int s3 = __shfl(src_all, eq + 12);
        f32x4 w0 = *(const f32x4*)&wlds[(unsigned)eq * 4];
        f32x4 w1 = *(const f32x4*)&wlds[(unsigned)(eq + 4) * 4];
        f32x4 w2 = *(const f32x4*)&wlds[(unsigned)(eq + 8) * 4];
        f32x4 w3 = *(const f32x4*)&wlds[(unsigned)(eq + 12) * 4];
        uint4 e0 = *(const uint4*)(hp + ((unsigned)s0 << 8));
        uint4 e1 = *(const uint4*)(hp + ((unsigned)s1 << 8));
        uint4 e2 = *(const uint4*)(hp + ((unsigned)s2 << 8));
        uint4 e3 = *(const uint4*)(hp + ((unsigned)s3 << 8));
        ACC4(e0, w0[0], w0[1], w0[2], w0[3]);
        ACC4(e1, w1[0], w1[1], w1[2], w1[3]);
        ACC4(e2, w2[0], w2[1], w2[2], w2[3]);
        ACC4(e3, w3[0], w3[1], w3[2], w3[3]);
        e += 16;
      } else {
        for (; e < bound; e += 4) {
          int gg = min(4, bound - e);
          int q4e = min(q4, gg - 1);
          int su = __shfl(src_all, e + q4e);
          f32x4 wv4 = *(const f32x4*)&wlds[(unsigned)(e + q4e) * 4];
          if (q4 >= gg) { wv4[0] = 0.f; wv4[1] = 0.f; wv4[2] = 0.f; wv4[3] = 0.f; }
          uint4 d = *(const uint4*)(hp + ((unsigned)su << 8));
          ACC4(d, wv4[0], wv4[1], wv4[2], wv4[3]);
        }
      }
    }
    // ---- normalize + transpose + A16 row write ----
    float dh0 = __shfl(den, 0), dh1 = __shfl(den, 16);
    float dh2 = __shfl(den, 32), dh3 = __shfl(den, 48);
    float i0 = 0.25f / (dh0 + 1e-16f), i1 = 0.25f / (dh1 + 1e-16f);
    float i2 = 0.25f / (dh2 + 1e-16f), i3 = 0.25f / (dh3 + 1e-16f);
    f32x4 v0 = {a[0].x * i0, a[0].y * i0, a[1].x * i0, a[1].y * i0};
    f32x4 v1 = {a[2].x * i1, a[2].y * i1, a[3].x * i1, a[3].y * i1};
    f32x4 v2 = {a[4].x * i2, a[4].y * i2, a[5].x * i2, a[5].y * i2};
    f32x4 v3 = {a[6].x * i3, a[6].y * i3, a[7].x * i3, a[7].y * i3};
    float* wb2 = &redw[(unsigned)lane * 16 + (lane & 7) * 4];
    *(f32x4*)(wb2 + 0) = v0;
    *(f32x4*)(wb2 + 4) = v1;
    *(f32x4*)(wb2 + 8) = v2;
    *(f32x4*)(wb2 + 12) = v3;
    __builtin_amdgcn_wave_barrier();
    int base = (lane & 15) * 16 + (lane & 7) * 4 + (lane >> 4);
    float s = 0.f;
#pragma unroll
    for (int q = 0; q < 4; ++q)
#pragma unroll
      for (int h = 0; h < 4; ++h)
        s += redw[q * 256 + base + 4 * h];
    A16[wv * 4 + nl][lane] = f2b(sigmoidf(s + b1[lane]));
    __builtin_amdgcn_wave_barrier();   // redw reads done before next node writes
  }
#undef PREFETCH_H8
  __syncthreads();                            // A16 complete; red dead -> ctile ok
  // ---- gemm2: wave wv owns N-tiles 4wv..4wv+3 (head == wv) ----
  int q = lane >> 4, r = lane & 15;
  bf16x8 a0 = *(const bf16x8*)&A16[r][q * 8];
  bf16x8 a1 = *(const bf16x8*)&A16[r][q * 8 + 32];
  f32x4 acc[4] = {};
#pragma unroll
  for (int ntl = 0; ntl < 4; ++ntl) {
    int ntg = wv * 4 + ntl;
    bf16x8 b0 = *(const bf16x8*)&W2b[(((unsigned)ntg * 2 + 0) * 64 + lane) * 8];
    bf16x8 bq = *(const bf16x8*)&W2b[(((unsigned)ntg * 2 + 1) * 64 + lane) * 8];
    acc[ntl] = __builtin_amdgcn_mfma_f32_16x16x32_bf16(a0, b0, acc[ntl], 0, 0, 0);
    acc[ntl] = __builtin_amdgcn_mfma_f32_16x16x32_bf16(a1, bq, acc[ntl], 0, 0, 0);
  }
  // attn dots for head wv
  float ps[4] = {}, pd[4] = {};
#pragma unroll
  for (int i = 0; i < 4; ++i) {
    float sv = as2[wv * 64 + i * 16 + r];
    float dv = ad2[wv * 64 + i * 16 + r];
#pragma unroll
    for (int reg = 0; reg < 4; ++reg) {
      ps[reg] += acc[i][reg] * sv;
      pd[reg] += acc[i][reg] * dv;
    }
  }
#pragma unroll
  for (int reg = 0; reg < 4; ++reg)
#pragma unroll
    for (int o = 1; o < 16; o <<= 1) {
      ps[reg] += __shfl_xor(ps[reg], o);
      pd[reg] += __shfl_xor(pd[reg], o);
    }
  if (r == 0) {
#pragma unroll
    for (int reg = 0; reg < 4; ++reg) {
      int row = blockIdx.x * 16 + q * 4 + reg;
      asrc2[row * 4 + wv] = ps[reg];
      adst2[row * 4 + wv] = pd[reg];
    }
  }
  // pack transposed C8 bytes p = r*16 + ntg through LDS, then coalesced store
#pragma unroll
  for (int reg = 0; reg < 4; ++reg) {
    int rowl = q * 4 + reg;
    int w = __builtin_amdgcn_cvt_pk_fp8_f32(acc[0][reg], acc[1][reg], 0, false);
    w = __builtin_amdgcn_cvt_pk_fp8_f32(acc[2][reg], acc[3][reg], w, true);
    sm.ctile[rowl * 64 + r * 4 + wv] = (unsigned)w;
  }
  __syncthreads();
  int row = threadIdx.x >> 4, seg = threadIdx.x & 15;
  uint4 v = *(const uint4*)&sm.ctile[row * 64 + seg * 4];
  *(uint4*)(h8b + ((size_t)(blockIdx.x * 16 + row)) * 256 + (unsigned)seg * 16) = v;
}

// ------- aggregation layer 2 (R26 core, writes bf16 out rows) -------------------
__global__ void aggregate_kernel(const unsigned char* __restrict__ h8,
                                 const float* __restrict__ asrc,
                                 const float* __restrict__ adst,
                                 const int* __restrict__ cnt,
                                 const unsigned short* __restrict__ csr_src,
                                 const float* __restrict__ bias,
                                 unsigned short* __restrict__ outb) {
  int wave = threadIdx.x >> 6, lane = threadIdx.x & 63;
  int node = blockIdx.x * 4 + wave;              // NN % 4 == 0: always valid
  __shared__ float wtab[4][256];
  __shared__ float red[4][1056];
  float s = agg_node(node, lane, wtab[wave], red[wave], h8, asrc, adst, cnt, csr_src);
  float ov = sigmoidf(s + bias[lane]);
  outb[(size_t)node * 64 + lane] = f2b(ov);     // 128B/wave coalesced
}

// ------- pool partial with FUSED gate MFMA (per-block, own chunk nodes) ----------
__global__ void pool_partial_kernel(const int* __restrict__ goffs,
                                    const unsigned short* __restrict__ out2b,
                                    const unsigned short* __restrict__ Bg,
                                    const float* __restrict__ gb1,
                                    const float* __restrict__ gamma,
                                    const float* __restrict__ beta,
                                    const float* __restrict__ gw2,
                                    const float* __restrict__ gb2,
                                    float* __restrict__ part_acc,
                                    float* __restrict__ part_den) {
  int b = blockIdx.x, j = blockIdx.y;
  int beg = goffs[b], end = goffs[b + 1];
  int chunk = (end - beg + CH - 1) / CH;
  int cb = beg + j * chunk;
  int ce = min(end, cb + chunk);
  int lane = threadIdx.x & 63, wave = threadIdx.x >> 6;
  int q = lane >> 4, r = lane & 15;
  const float s = rsqrtf(1.f + 1e-5f);
  float gb2v = gb2[0];
  float accv = 0.f, den = 0.f;
  for (int n0 = cb + wave * 16; n0 < ce; n0 += 64) {
    // gate MFMA for nodes n0..n0+15
    f32x4 acc[4] = {};
    int row = n0 + r;
    if (row >= NN) row = NN - 1;
    const unsigned short* Arow = out2b + (size_t)row * 64 + q * 8;
#pragma unroll
    for (int kc = 0; kc < 2; ++kc) {
      bf16x8 a = *(const bf16x8*)(Arow + kc * 32);
#pragma unroll
      for (int nt = 0; nt < 4; ++nt) {
        bf16x8 b8 = *(const bf16x8*)&Bg[(((size_t)nt * 2 + kc) * 64 + lane) * 8];
        acc[nt] = __builtin_amdgcn_mfma_f32_16x16x32_bf16(a, b8, acc[nt], 0, 0, 0);
      }
    }
    float sum[4] = {0.f, 0.f, 0.f, 0.f};
#pragma unroll
    for (int nt = 0; nt < 4; ++nt) {
      int col = nt * 16 + r;
      float off = gb1[col] * gamma[col] * s + beta[col];
      float w2 = gw2[col];
#pragma unroll
      for (int reg = 0; reg < 4; ++reg)
        sum[reg] += fmaxf(acc[nt][reg] + off, 0.f) * w2;
    }
#pragma unroll
    for (int reg = 0; reg < 4; ++reg)
#pragma unroll
      for (int o = 1; o < 16; o <<= 1) sum[reg] += __shfl_xor(sum[reg], o);
    float gx[4];
#pragma unroll
    for (int reg = 0; reg < 4; ++reg) {
      int n = n0 + q * 4 + reg;
      gx[reg] = (n < ce) ? __expf(sum[reg] + gb2v) : 0.f;
    }
#pragma unroll
    for (int t = 0; t < 16; ++t) {
      int n = n0 + t;
      if (n >= ce) break;
      float gv = __shfl(gx[t & 3], (t >> 2) << 4);
      accv += gv * b2f(out2b[(size_t)n * 64 + lane]);
      den += gv;  // identical on all lanes
    }
  }
  __shared__ float sacc[4][64];
  __shared__ float sden[4];
  sacc[wave][lane] = accv;
  if (lane == 0) sden[wave] = den;
  __syncthreads();
  if (wave == 0) {
    float a = sacc[0][lane] + sacc[1][lane] + sacc[2][lane] + sacc[3][lane];
    part_acc[((size_t)b * CH + j) * 64 + lane] = a;
    if (lane == 0) part_den[b * CH + j] = sden[0] + sden[1] + sden[2] + sden[3];
  }
}

__global__ void pool_final_kernel(const float* __restrict__ part_acc,
                                  const float* __restrict__ part_den,
                                  const float* __restrict__ lw, const float* __restrict__ lb,
                                  float* __restrict__ out) {
  int b = blockIdx.x, lane = threadIdx.x;  // 64 threads
  float a = 0.f;
#pragma unroll
  for (int j = 0; j < CH; ++j) a += part_acc[((size_t)b * CH + j) * 64 + lane];
  float den = (lane < CH) ? part_den[b * CH + lane] : 0.f;
  den = wred(den);
  den = __shfl(den, 0);
  float p = a / (den + 1e-16f);
  float v = wred(p * lw[lane]);
  if (lane == 0) out[b] = sigmoidf(v + lb[0]);
}

extern "C" void kernel_launch(void* const* d_in, const int* in_sizes, int n_in,
                              void* d_out, int out_size, void* d_ws, size_t ws_size,
                              hipStream_t stream) {
  const float* x    = (const float*)d_in[0];
  const int*   ei   = (const int*)d_in[1];
  const int*   batch= (const int*)d_in[2];
  const float* W1   = (const float*)d_in[4];
  const float* as1  = (const float*)d_in[5];
  const float* ad1  = (const float*)d_in[6];
  const float* b1   = (const float*)d_in[7];
  const float* W2   = (const float*)d_in[8];
  const float* as2  = (const float*)d_in[9];
  const float* ad2  = (const float*)d_in[10];
  const float* b2   = (const float*)d_in[11];
  const float* gw1  = (const float*)d_in[12];
  const float* gb1  = (const float*)d_in[13];
  const float* gamma= (const float*)d_in[14];
  const float* beta = (const float*)d_in[15];
  const float* gw2  = (const float*)d_in[16];
  const float* gb2  = (const float*)d_in[17];
  const float* lw   = (const float*)d_in[18];
  const float* lb   = (const float*)d_in[19];
  float* out = (float*)d_out;

  char* ws = (char*)d_ws;
  size_t off = 0;
  auto alloc = [&](size_t bytes) -> void* {
    void* p = ws + off;
    off = (off + bytes + 255) & ~(size_t)255;
    return p;
  };
  unsigned short* W1b    = (unsigned short*)alloc((size_t)128 * 256 * 2);
  unsigned short* W2b    = (unsigned short*)alloc((size_t)64 * 256 * 2);
  unsigned short* Bg     = (unsigned short*)alloc((size_t)64 * 64 * 2);
  unsigned char*  h8     = (unsigned char*)alloc((size_t)NN * 256);
  unsigned char*  h8b    = (unsigned char*)alloc((size_t)NN * 256);
  unsigned short* out2b  = (unsigned short*)alloc((size_t)NN * 64 * 2);
  float*    asrc    = (float*)alloc((size_t)NN * 4 * 4);
  float*    adst    = (float*)alloc((size_t)NN * 4 * 4);
  float*    asrc2   = (float*)alloc((size_t)NN * 4 * 4);
  float*    adst2   = (float*)alloc((size_t)NN * 4 * 4);
  int*      cnt     = (int*)alloc((size_t)NN * 4);
  unsigned short* csr16 = (unsigned short*)alloc((size_t)NN * SLOTS * 2);
  unsigned* bins    = (unsigned*)alloc((size_t)EBN * NBKT * CAP * 4);
  int*      binCnt  = (int*)alloc((size_t)EBN * NBKT * 4);
  int*      ovf_cnt = (int*)alloc(256);
  unsigned* ovf     = (unsigned*)alloc((size_t)OVFCAP * 4);
  int*      goffs   = (int*)alloc((size_t)(NG + 1) * 4);
  float*    pacc    = (float*)alloc((size_t)NG * CH * 64 * 4);
  float*    pden    = (float*)alloc((size_t)NG * CH * 4);

  // prep: packs + bounds + ovf zero
  prep_kernel<<<209, 256, 0, stream>>>(W1, W2, gw1, gamma, batch,
                                       W1b, W2b, Bg, goffs, ovf_cnt);

  // Layer 1 GEMM + atomic-free bucket histogram (pass A) overlapped in one launch
  gemm1_build_kernel<<<GB + EBN, 256, 0, stream>>>(x, W1b, h8, as1, ad1, asrc, adst,
                                                   ei, bins, binCnt, ovf_cnt, ovf);
  // pass C: finalize csr + cnt per bucket (plain stores, LDS ranks)
  csr_build_kernel<<<NBKT, 1024, 0, stream>>>(bins, binCnt, ovf_cnt, ovf, csr16, cnt);

  // FUSED aggregate1 + gemm2 + attn2 (block = 16 nodes, cross-node prefetch)
  agg1_gemm2_kernel<<<MT, 256, 0, stream>>>(h8, asrc, adst, cnt, csr16, b1,
                                            W2b, as2, ad2, h8b, asrc2, adst2);

  // Layer 2 aggregation
  aggregate_kernel<<<NN / 4, 256, 0, stream>>>(h8b, asrc2, adst2, cnt, csr16, b2, out2b);

  // Global attention pooling (gate MFMA fused into partial)
  pool_partial_kernel<<<dim3(NG, CH), 256, 0, stream>>>(goffs, out2b, Bg, gb1, gamma, beta,
                                                        gw2, gb2, pacc, pden);
  pool_final_kernel<<<NG, 64, 0, stream>>>(pacc, pden, lw, lb, out);
}

// Round 11
// 235.687 us; speedup vs baseline: 1.1180x; 1.1180x over previous
//
#include <hip/hip_runtime.h>

// GAT forward (2x GATConv + GlobalAttention pool) for MI355X.
// R28 = R26 + cross-node prefetch RETRY with the R27 spill fixed (R27 diag:
// WRITE_SIZE 14->94MB @ VGPR=64 = dbuf spilled to scratch; allocator targeted
// 8 waves/SIMD without launch_bounds):
//   - __launch_bounds__(256,2) on agg1_gemm2: VGPR cap 256 (occupancy is
//     LDS-limited to 6 blocks/CU anyway; achieved was ~2.7 waves/SIMD).
//   - cross-node buffer shrunk to quarter-0 only (p0[2][4], 32 VGPRs,
//     UNCONDITIONAL clamped loads -> simple liveness); quarter-1 stays as
//     R26's short-lived intra-node hoist. Expected pressure ~110-130 VGPR.
//   - aggregate_kernel keeps R26 agg_node unchanged. 7 launches.

constexpr int NN = 50000;          // nodes
constexpr int EE = 800000;         // edges (without self loops)
constexpr int NG = 64;             // graphs
constexpr float NEG = 0.2f;       // leaky relu slope
constexpr int MT = NN / 16;        // 3125 m-tiles (NN % 16 == 0)
constexpr int SLOTS = 64;          // CSR slots per node; P(deg>64) ~ 0 (Poisson(16)+1)
constexpr int CH = 16;             // pool chunks per graph
constexpr int GB = (MT + 3) / 4;   // gemm blocks (wave per m-tile, 4 waves/block)

constexpr int EB_EDGES = 4096;                     // edges per hist block
constexpr int EBN = (EE + EB_EDGES - 1) / EB_EDGES; // 196 hist blocks
constexpr int NBKT = (NN + 255) / 256;             // 196 coarse buckets (dst>>8)
constexpr int CAP = 48;            // bin capacity; Poisson(20.9), P(>48)*bins ~ 0.1
constexpr int OVFCAP = 8192;       // overflow fallback list

static_assert(NN % 16 == 0, "fused block = 16 nodes");

using bf16x8 = __attribute__((ext_vector_type(8))) __bf16;
using f32x4  = __attribute__((ext_vector_type(4))) float;
using f32x2  = __attribute__((ext_vector_type(2))) float;

__device__ __forceinline__ float wred(float v) {
#pragma unroll
  for (int o = 32; o; o >>= 1) v += __shfl_down(v, o);
  return v;
}
__device__ __forceinline__ float sigmoidf(float v) { return 1.f / (1.f + __expf(-v)); }
__device__ __forceinline__ float lrelu(float v) { return fmaxf(v, NEG * v); }
__device__ __forceinline__ unsigned short f2b(float f) {
  union { float f; unsigned u; } v; v.f = f;
  unsigned r = v.u + 0x7fff + ((v.u >> 16) & 1);
  return (unsigned short)(r >> 16);
}
__device__ __forceinline__ float b2f(unsigned short b) {
  union { unsigned u; float f; } v; v.u = ((unsigned)b) << 16;
  return v.f;
}

// ------- prep: pack W1/W2/gateW + graph bounds + zero ovf counter ---------------
__global__ void prep_kernel(const float* __restrict__ W1, const float* __restrict__ W2,
                            const float* __restrict__ gw1, const float* __restrict__ gamma,
                            const int* __restrict__ batch,
                            unsigned short* __restrict__ W1b, unsigned short* __restrict__ W2b,
                            unsigned short* __restrict__ Bg, int* __restrict__ goffs,
                            int* __restrict__ ovf_cnt) {
  int b = blockIdx.x;
  if (b < 128) {  // W1 pack: K=128, KC=4, N=256
    int idx = b * 256 + threadIdx.x;
    int j = idx & 7, lane = (idx >> 3) & 63, rest = idx >> 9;
    int kc = rest & 3, ntile = rest >> 2;
    W1b[idx] = f2b(W1[(kc * 32 + (lane >> 4) * 8 + j) * 256 + ntile * 16 + (lane & 15)]);
    return;
  }
  if (b < 192) {  // W2 pack: K=64, KC=2, N=256
    int idx = (b - 128) * 256 + threadIdx.x;
    int j = idx & 7, lane = (idx >> 3) & 63, rest = idx >> 9;
    int kc = rest & 1, ntile = rest >> 1;
    W2b[idx] = f2b(W2[(kc * 32 + (lane >> 4) * 8 + j) * 256 + ntile * 16 + (lane & 15)]);
    return;
  }
  if (b < 208) {  // gate W pack: K=64, KC=2, N=64, BN scale folded
    int idx = (b - 192) * 256 + threadIdx.x;  // 0..4095
    int j = idx & 7, lane = (idx >> 3) & 63, rest = idx >> 9;
    int kc = rest & 1, nt = rest >> 1;
    int k = kc * 32 + (lane >> 4) * 8 + j;
    int n = nt * 16 + (lane & 15);
    Bg[idx] = f2b(gw1[k * 64 + n] * gamma[n] * rsqrtf(1.f + 1e-5f));
    return;
  }
  // graph bounds (sorted batch, binary search) + ovf counter zero
  if (threadIdx.x == 0) *ovf_cnt = 0;
  int g = threadIdx.x;
  if (g <= NG) {
    int lo = 0, hi = NN;
    while (lo < hi) {
      int mid = (lo + hi) >> 1;
      if (batch[mid] < g) lo = mid + 1; else hi = mid;
    }
    goffs[g] = lo;
  }
}

// ------- MFMA GEMM body: A in regs, B in LDS, fused attn, TRANSPOSED fp8 C ------
template <int KC>
__device__ __forceinline__ void gemm_body(int mt, int lane, const bf16x8* av,
                                          const unsigned short* Bp,  // LDS
                                          unsigned char* __restrict__ C8,
                                          const float* __restrict__ att_s,
                                          const float* __restrict__ att_d,
                                          float* __restrict__ asrc,
                                          float* __restrict__ adst) {
  int m0 = mt * 16;
  int q = lane >> 4, r = lane & 15;
  f32x4 acc[16] = {};
#pragma unroll
  for (int kc = 0; kc < KC; ++kc) {
#pragma unroll
    for (int nt = 0; nt < 16; ++nt) {
      bf16x8 b = *(const bf16x8*)&Bp[(((unsigned)nt * KC + kc) * 64 + lane) * 8];
      acc[nt] = __builtin_amdgcn_mfma_f32_16x16x32_bf16(av[kc], b, acc[nt], 0, 0, 0);
    }
  }
  // transposed C8 store: byte p = r*16 + nt  (true channel c = nt*16 + r)
#pragma unroll
  for (int reg = 0; reg < 4; ++reg) {
    unsigned row = m0 + q * 4 + reg;
    uint4 pk;
    int w;
    w = __builtin_amdgcn_cvt_pk_fp8_f32(acc[0][reg], acc[1][reg], 0, false);
    w = __builtin_amdgcn_cvt_pk_fp8_f32(acc[2][reg], acc[3][reg], w, true);
    pk.x = (unsigned)w;
    w = __builtin_amdgcn_cvt_pk_fp8_f32(acc[4][reg], acc[5][reg], 0, false);
    w = __builtin_amdgcn_cvt_pk_fp8_f32(acc[6][reg], acc[7][reg], w, true);
    pk.y = (unsigned)w;
    w = __builtin_amdgcn_cvt_pk_fp8_f32(acc[8][reg], acc[9][reg], 0, false);
    w = __builtin_amdgcn_cvt_pk_fp8_f32(acc[10][reg], acc[11][reg], w, true);
    pk.z = (unsigned)w;
    w = __builtin_amdgcn_cvt_pk_fp8_f32(acc[12][reg], acc[13][reg], 0, false);
    w = __builtin_amdgcn_cvt_pk_fp8_f32(acc[14][reg], acc[15][reg], w, true);
    pk.w = (unsigned)w;
    *(uint4*)(C8 + (size_t)row * 256 + (unsigned)r * 16) = pk;
  }
  // fused attention dots (true-channel order)
  float ps[4][4] = {}, pd[4][4] = {};
#pragma unroll
  for (int head = 0; head < 4; ++head) {
#pragma unroll
    for (int i = 0; i < 4; ++i) {
      float sv = att_s[head * 64 + i * 16 + r];
      float dv = att_d[head * 64 + i * 16 + r];
#pragma unroll
      for (int reg = 0; reg < 4; ++reg) {
        ps[head][reg] += acc[head * 4 + i][reg] * sv;
        pd[head][reg] += acc[head * 4 + i][reg] * dv;
      }
    }
  }
#pragma unroll
  for (int head = 0; head < 4; ++head)
#pragma unroll
    for (int reg = 0; reg < 4; ++reg)
#pragma unroll
      for (int o = 1; o < 16; o <<= 1) {
        ps[head][reg] += __shfl_xor(ps[head][reg], o);
        pd[head][reg] += __shfl_xor(pd[head][reg], o);
      }
  if (r == 0) {
#pragma unroll
    for (int reg = 0; reg < 4; ++reg) {
      int row = m0 + q * 4 + reg;
#pragma unroll
      for (int head = 0; head < 4; ++head) {
        asrc[row * 4 + head] = ps[head][reg];
        adst[row * 4 + head] = pd[head][reg];
      }
    }
  }
}

// ------- GEMM1 (LDS-staged B) + atomic-free bucket-histogram pass A -------------
__global__ void gemm1_build_kernel(const float* __restrict__ x,
                                   const unsigned short* __restrict__ W1b,
                                   unsigned char* __restrict__ C8,
                                   const float* __restrict__ att_s,
                                   const float* __restrict__ att_d,
                                   float* __restrict__ asrc, float* __restrict__ adst,
                                   const int* __restrict__ ei,
                                   unsigned* __restrict__ bins,
                                   int* __restrict__ binCnt,
                                   int* __restrict__ ovf_cnt,
                                   unsigned* __restrict__ ovf) {
  __shared__ union {
    unsigned short B[128 * 256];   // 64 KB staged W1b
    int hist[NBKT];
  } smem;
  int b = blockIdx.x;
  if (b < GB) {
    int wave = threadIdx.x >> 6, lane = threadIdx.x & 63;
    int mt0 = b * 4 + wave;
    int mt = min(mt0, MT - 1);      // tail waves load safe addr, exit after barrier
    int q = lane >> 4, r = lane & 15;
    // stage B (all 256 threads; 16 x uint4 each)
#pragma unroll
    for (int it = 0; it < 16; ++it)
      ((uint4*)smem.B)[it * 256 + threadIdx.x] = ((const uint4*)W1b)[it * 256 + threadIdx.x];
    // hoisted A load + bf16 convert (overlaps staging; barrier drains all)
    bf16x8 av[4];
    {
      const float* Arow = x + (size_t)(mt * 16 + r) * 128 + q * 8;
      float4 f0[4], f1[4];
#pragma unroll
      for (int kc = 0; kc < 4; ++kc) {
        f0[kc] = *(const float4*)(Arow + kc * 32);
        f1[kc] = *(const float4*)(Arow + kc * 32 + 4);
      }
#pragma unroll
      for (int kc = 0; kc < 4; ++kc) {
        union { bf16x8 v; unsigned short s[8]; } u;
        u.s[0] = f2b(f0[kc].x); u.s[1] = f2b(f0[kc].y);
        u.s[2] = f2b(f0[kc].z); u.s[3] = f2b(f0[kc].w);
        u.s[4] = f2b(f1[kc].x); u.s[5] = f2b(f1[kc].y);
        u.s[6] = f2b(f1[kc].z); u.s[7] = f2b(f1[kc].w);
        av[kc] = u.v;
      }
    }
    __syncthreads();
    if (mt0 >= MT) return;
    gemm_body<4>(mt, lane, av, smem.B, C8, att_s, att_d, asrc, adst);
    return;
  }
  // pass A: per-block LDS histogram over coarse buckets, LDS ranks, bin scatter
  int hb = b - GB;
  for (int t = threadIdx.x; t < NBKT; t += 256) smem.hist[t] = 0;
  __syncthreads();
  int e0 = hb * EB_EDGES + threadIdx.x * 16;
#pragma unroll
  for (int k4 = 0; k4 < 4; ++k4) {
    int e = e0 + k4 * 4;
    if (e >= EE) break;
    int4 s4 = *(const int4*)&ei[e];
    int4 d4 = *(const int4*)&ei[EE + e];
    int ss[4] = {s4.x, s4.y, s4.z, s4.w};
    int dd[4] = {d4.x, d4.y, d4.z, d4.w};
#pragma unroll
    for (int u = 0; u < 4; ++u) {
      if (e + u >= EE) break;
      int src = ss[u], dst = dd[u];
      int bkt = dst >> 8;
      int rr = atomicAdd(&smem.hist[bkt], 1);   // LDS atomic — stays in the CU
      if (rr < CAP) {
        bins[((unsigned)hb * NBKT + bkt) * CAP + rr] =
            (unsigned)src | ((unsigned)(dst & 255) << 16);
      } else {  // statistically ~never; bulletproof fallback
        int o = atomicAdd(ovf_cnt, 1);
        if (o < OVFCAP) ovf[o] = (unsigned)src | ((unsigned)dst << 16);
      }
    }
  }
  __syncthreads();
  for (int t = threadIdx.x; t < NBKT; t += 256) binCnt[hb * NBKT + t] = smem.hist[t];
}

// ------- pass C: per-bucket CSR finalization (plain stores, LDS ranks) ----------
__global__ __launch_bounds__(1024) void csr_build_kernel(
    const unsigned* __restrict__ bins, const int* __restrict__ binCnt,
    const int* __restrict__ ovf_cnt, const unsigned* __restrict__ ovf,
    unsigned short* __restrict__ csr16, int* __restrict__ cnt) {
  int b = blockIdx.x;                 // bucket = nodes [b*256, b*256+256)
  __shared__ int hist[256];
  int t = threadIdx.x;
  int node0 = b << 8;
  if (t < 256) {
    hist[t] = 1;                      // slot 0 reserved for the self loop
    int node = node0 + t;
    if (node < NN) csr16[(unsigned)node * SLOTS] = (unsigned short)node;
  }
  __syncthreads();
  int wave = t >> 6, lane = t & 63;
  for (int i = wave; i < EBN; i += 16) {
    int c = binCnt[i * NBKT + b];
    if (c > CAP) c = CAP;
    for (int base = 0; base < c; base += 64) {
      int j = base + lane;
      if (j < c) {
        unsigned p = bins[((unsigned)i * NBKT + b) * CAP + j];
        int dl = p >> 16, src = p & 0xffff;
        int r = atomicAdd(&hist[dl], 1);
        if (r < SLOTS) csr16[(unsigned)(node0 + dl) * SLOTS + r] = (unsigned short)src;
      }
    }
  }
  __syncthreads();
  int oc = *ovf_cnt;
  if (oc > OVFCAP) oc = OVFCAP;
  for (int j = t; j < oc; j += 1024) {
    unsigned p = ovf[j];
    int dst = (int)(p >> 16);
    if ((dst >> 8) == b) {
      int r = atomicAdd(&hist[dst & 255], 1);
      if (r < SLOTS) csr16[(unsigned)dst * SLOTS + r] = (unsigned short)(p & 0xffff);
    }
  }
  __syncthreads();
  if (t < 256) {
    int node = node0 + t;
    if (node < NN) cnt[node] = hist[t];
  }
}

// ------- accumulate macro shared by both aggregate paths ------------------------
#define ACC4(d, wA, wB, wC, wD)                                              \
  {                                                                          \
    a[0] += __builtin_amdgcn_cvt_pk_f32_fp8((d).x, false) * (wA);            \
    a[1] += __builtin_amdgcn_cvt_pk_f32_fp8((d).x, true) * (wA);             \
    a[2] += __builtin_amdgcn_cvt_pk_f32_fp8((d).y, false) * (wB);            \
    a[3] += __builtin_amdgcn_cvt_pk_f32_fp8((d).y, true) * (wB);             \
    a[4] += __builtin_amdgcn_cvt_pk_f32_fp8((d).z, false) * (wC);            \
    a[5] += __builtin_amdgcn_cvt_pk_f32_fp8((d).z, true) * (wC);             \
    a[6] += __builtin_amdgcn_cvt_pk_f32_fp8((d).w, false) * (wD);            \
    a[7] += __builtin_amdgcn_cvt_pk_f32_fp8((d).w, true) * (wD);             \
  }

// ------- aggregate core for ONE node on ONE wave (R26 hoisted gathers) ----------
__device__ __forceinline__ float agg_node(int node, int lane,
                                          float* __restrict__ wlds,   // [256] per wave
                                          float* __restrict__ redw,   // [1056] per wave
                                          const unsigned char* __restrict__ h8,
                                          const float* __restrict__ asrc,
                                          const float* __restrict__ adst,
                                          const int* __restrict__ cnt,
                                          const unsigned short* __restrict__ csr_src) {
  int q4 = lane >> 4, r16 = lane & 15, hgrp = q4;
  int deg = min(cnt[node], SLOTS);
  float adh = adst[node * 4 + hgrp];
  int src_all = csr_src[(unsigned)node * SLOTS + lane];  // coalesced 128B load
  int dm1 = deg - 1;                                     // deg >= 1 (self loop)
  const unsigned char* hp = h8 + (unsigned)r16 * 16;
  uint4 d0, d1, d2, d3, d4, d5, d6, d7;
  {
    int s0 = __shfl(src_all, min(q4, dm1));
    int s1 = __shfl(src_all, min(q4 + 4, dm1));
    int s2 = __shfl(src_all, min(q4 + 8, dm1));
    int s3 = __shfl(src_all, min(q4 + 12, dm1));
    d0 = *(const uint4*)(hp + ((unsigned)s0 << 8));
    d1 = *(const uint4*)(hp + ((unsigned)s1 << 8));
    d2 = *(const uint4*)(hp + ((unsigned)s2 << 8));
    d3 = *(const uint4*)(hp + ((unsigned)s3 << 8));
  }
  bool haveQ1 = deg > 16;                               // wave-uniform
  if (haveQ1) {
    int s4 = __shfl(src_all, min(q4 + 16, dm1));
    int s5 = __shfl(src_all, min(q4 + 20, dm1));
    int s6 = __shfl(src_all, min(q4 + 24, dm1));
    int s7 = __shfl(src_all, min(q4 + 28, dm1));
    d4 = *(const uint4*)(hp + ((unsigned)s4 << 8));
    d5 = *(const uint4*)(hp + ((unsigned)s5 << 8));
    d6 = *(const uint4*)(hp + ((unsigned)s6 << 8));
    d7 = *(const uint4*)(hp + ((unsigned)s7 << 8));
  }
  float den = 0.f;
#pragma unroll
  for (int i = 0; i < 4; ++i) {
    int slot = i * 16 + r16;
    float w = 0.f;
    if (i * 16 < deg) {                          // wave-uniform skip (deg~17)
      int s = __shfl(src_all, slot);
      bool valid = slot < deg;
      float xv = asrc[(unsigned)(valid ? s : 0) * 4 + hgrp];
      w = valid ? __expf(lrelu(xv + adh)) : 0.f;
    }
    wlds[slot * 4 + hgrp] = w;                   // ALWAYS written (0 if invalid)
    den += w;
  }
#pragma unroll
  for (int o = 1; o < 16; o <<= 1) den += __shfl_xor(den, o);  // den per head hgrp
  __builtin_amdgcn_wave_barrier();               // keep write->read order (intra-wave)

  f32x2 a[8] = {};
  {
    f32x4 w0 = *(const f32x4*)&wlds[(unsigned)q4 * 4];
    f32x4 w1 = *(const f32x4*)&wlds[(unsigned)(q4 + 4) * 4];
    f32x4 w2 = *(const f32x4*)&wlds[(unsigned)(q4 + 8) * 4];
    f32x4 w3 = *(const f32x4*)&wlds[(unsigned)(q4 + 12) * 4];
    ACC4(d0, w0[0], w0[1], w0[2], w0[3]);
    ACC4(d1, w1[0], w1[1], w1[2], w1[3]);
    ACC4(d2, w2[0], w2[1], w2[2], w2[3]);
    ACC4(d3, w3[0], w3[1], w3[2], w3[3]);
  }
  if (haveQ1) {
    f32x4 w0 = *(const f32x4*)&wlds[(unsigned)(q4 + 16) * 4];
    f32x4 w1 = *(const f32x4*)&wlds[(unsigned)(q4 + 20) * 4];
    f32x4 w2 = *(const f32x4*)&wlds[(unsigned)(q4 + 24) * 4];
    f32x4 w3 = *(const f32x4*)&wlds[(unsigned)(q4 + 28) * 4];
    ACC4(d4, w0[0], w0[1], w0[2], w0[3]);
    ACC4(d5, w1[0], w1[1], w1[2], w1[3]);
    ACC4(d6, w2[0], w2[1], w2[2], w2[3]);
    ACC4(d7, w3[0], w3[1], w3[2], w3[3]);
  }
  // quarters 2-3 (deg > 32, rare): late-load path
  int e = 32;
#pragma unroll
  for (int i = 2; i < 4; ++i) {
    if (e >= deg) break;
    int bound = min(deg, (i + 1) * 16);
    if (bound - e == 16) {
      int eq = e + q4;
      int s0 = __shfl(src_all, eq);
      int s1 = __shfl(src_all, eq + 4);
      int s2 = __shfl(src_all, eq + 8);
      int s3 = __shfl(src_all, eq + 12);
      f32x4 w0 = *(const f32x4*)&wlds[(unsigned)eq * 4];
      f32x4 w1 = *(const f32x4*)&wlds[(unsigned)(eq + 4) * 4];
      f32x4 w2 = *(const f32x4*)&wlds[(unsigned)(eq + 8) * 4];
      f32x4 w3 = *(const f32x4*)&wlds[(unsigned)(eq + 12) * 4];
      uint4 e0 = *(const uint4*)(hp + ((unsigned)s0 << 8));
      uint4 e1 = *(const uint4*)(hp + ((unsigned)s1 << 8));
      uint4 e2 = *(const uint4*)(hp + ((unsigned)s2 << 8));
      uint4 e3 = *(const uint4*)(hp + ((unsigned)s3 << 8));
      ACC4(e0, w0[0], w0[1], w0[2], w0[3]);
      ACC4(e1, w1[0], w1[1], w1[2], w1[3]);
      ACC4(e2, w2[0], w2[1], w2[2], w2[3]);
      ACC4(e3, w3[0], w3[1], w3[2], w3[3]);
      e += 16;
    } else {
      for (; e < bound; e += 4) {
        int gg = min(4, bound - e);
        int q4e = min(q4, gg - 1);
        int su = __shfl(src_all, e + q4e);
        f32x4 wv = *(const f32x4*)&wlds[(unsigned)(e + q4e) * 4];
        if (q4 >= gg) { wv[0] = 0.f; wv[1] = 0.f; wv[2] = 0.f; wv[3] = 0.f; }
        uint4 d = *(const uint4*)(hp + ((unsigned)su << 8));
        ACC4(d, wv[0], wv[1], wv[2], wv[3]);
      }
    }
  }
  // per-head normalize (0.25 = head-mean folded), then LDS transpose
  float dh0 = __shfl(den, 0), dh1 = __shfl(den, 16);
  float dh2 = __shfl(den, 32), dh3 = __shfl(den, 48);
  float i0 = 0.25f / (dh0 + 1e-16f), i1 = 0.25f / (dh1 + 1e-16f);
  float i2 = 0.25f / (dh2 + 1e-16f), i3 = 0.25f / (dh3 + 1e-16f);
  f32x4 v0 = {a[0].x * i0, a[0].y * i0, a[1].x * i0, a[1].y * i0};
  f32x4 v1 = {a[2].x * i1, a[2].y * i1, a[3].x * i1, a[3].y * i1};
  f32x4 v2 = {a[4].x * i2, a[4].y * i2, a[5].x * i2, a[5].y * i2};
  f32x4 v3 = {a[6].x * i3, a[6].y * i3, a[7].x * i3, a[7].y * i3};
  float* wb2 = &redw[(unsigned)lane * 16 + (lane & 7) * 4];
  *(f32x4*)(wb2 + 0) = v0;
  *(f32x4*)(wb2 + 4) = v1;
  *(f32x4*)(wb2 + 8) = v2;
  *(f32x4*)(wb2 + 12) = v3;
  __builtin_amdgcn_wave_barrier();
  int base = (lane & 15) * 16 + (lane & 7) * 4 + (lane >> 4);
  float s = 0.f;
#pragma unroll
  for (int q = 0; q < 4; ++q)
#pragma unroll
    for (int h = 0; h < 4; ++h)
      s += redw[q * 256 + base + 4 * h];
  return s;
}

// ------- FUSED aggregate1 + gemm2 + attn2: 16 nodes, q0 x-node prefetch ---------
__global__ __launch_bounds__(256, 2)
void agg1_gemm2_kernel(const unsigned char* __restrict__ h8,
                       const float* __restrict__ asrc1,
                       const float* __restrict__ adst1,
                       const int* __restrict__ cnt,
                       const unsigned short* __restrict__ csr_src,
                       const float* __restrict__ b1,
                       const unsigned short* __restrict__ W2b,
                       const float* __restrict__ as2,
                       const float* __restrict__ ad2,
                       unsigned char* __restrict__ h8b,
                       float* __restrict__ asrc2,
                       float* __restrict__ adst2) {
  int wv = threadIdx.x >> 6, lane = threadIdx.x & 63;
  int q4 = lane >> 4, r16 = lane & 15, hgrp = q4;
  __shared__ float wtab[4][256];
  __shared__ union { float red[4][1056]; unsigned ctile[16 * 64]; } sm;
  __shared__ unsigned short A16[16][72];     // out1 tile, +8 pad per row
  const unsigned char* hp = h8 + (unsigned)r16 * 16;
  float* wlds = wtab[wv];
  float* redw = sm.red[wv];

  // ---- preload all 4 nodes' scalars (independent; overlapping chains) ----
  int node0 = blockIdx.x * 16 + wv * 4;
  int srcA[4], degA[4];
  float adhA[4];
#pragma unroll
  for (int nl = 0; nl < 4; ++nl) {
    srcA[nl] = csr_src[(unsigned)(node0 + nl) * SLOTS + lane];
    degA[nl] = min(cnt[node0 + nl], SLOTS);
    adhA[nl] = adst1[(node0 + nl) * 4 + hgrp];
  }
  // quarter-0 cross-node prefetch buffer (UNCONDITIONAL clamped loads)
#define PRE_Q0(sa, degv, dd)                                                 \
  {                                                                          \
    int dm1p = (degv) - 1;                                                   \
    int s0 = __shfl(sa, min(q4, dm1p));                                      \
    int s1 = __shfl(sa, min(q4 + 4, dm1p));                                  \
    int s2 = __shfl(sa, min(q4 + 8, dm1p));                                  \
    int s3 = __shfl(sa, min(q4 + 12, dm1p));                                 \
    dd[0] = *(const uint4*)(hp + ((unsigned)s0 << 8));                       \
    dd[1] = *(const uint4*)(hp + ((unsigned)s1 << 8));                       \
    dd[2] = *(const uint4*)(hp + ((unsigned)s2 << 8));                       \
    dd[3] = *(const uint4*)(hp + ((unsigned)s3 << 8));                       \
  }
  uint4 p0[2][4];
  PRE_Q0(srcA[0], degA[0], p0[0]);
#pragma unroll
  for (int nl = 0; nl < 4; ++nl) {
    const int cur = nl & 1, nxt = cur ^ 1;   // compile-time after unroll
    if (nl < 3) PRE_Q0(srcA[nl + 1], degA[nl + 1], p0[nxt]);
    int src_all = srcA[nl], deg = degA[nl];
    float adh = adhA[nl];
    int dm1 = deg - 1;
    // ---- intra-node q1 hoist (R26 style; short register lifetime) ----
    bool haveQ1 = deg > 16;                  // wave-uniform
    uint4 dq1[4];
    if (haveQ1) {
      int s4 = __shfl(src_all, min(q4 + 16, dm1));
      int s5 = __shfl(src_all, min(q4 + 20, dm1));
      int s6 = __shfl(src_all, min(q4 + 24, dm1));
      int s7 = __shfl(src_all, min(q4 + 28, dm1));
      dq1[0] = *(const uint4*)(hp + ((unsigned)s4 << 8));
      dq1[1] = *(const uint4*)(hp + ((unsigned)s5 << 8));
      dq1[2] = *(const uint4*)(hp + ((unsigned)s6 << 8));
      dq1[3] = *(const uint4*)(hp + ((unsigned)s7 << 8));
    }
    // ---- weight phase (prefetched gathers in flight) ----
    float den = 0.f;
#pragma unroll
    for (int i = 0; i < 4; ++i) {
      int slot = i * 16 + r16;
      float w = 0.f;
      if (i * 16 < deg) {
        int s = __shfl(src_all, slot);
        bool valid = slot < deg;
        float xv = asrc1[(unsigned)(valid ? s : 0) * 4 + hgrp];
        w = valid ? __expf(lrelu(xv + adh)) : 0.f;
      }
      wlds[slot * 4 + hgrp] = w;
      den += w;
    }
#pragma unroll
    for (int o = 1; o < 16; o <<= 1) den += __shfl_xor(den, o);
    __builtin_amdgcn_wave_barrier();
    // ---- accumulate: q0 from p0[cur], q1 from dq1, q2-3 late ----
    f32x2 a[8] = {};
    {
      f32x4 w0 = *(const f32x4*)&wlds[(unsigned)q4 * 4];
      f32x4 w1 = *(const f32x4*)&wlds[(unsigned)(q4 + 4) * 4];
      f32x4 w2 = *(const f32x4*)&wlds[(unsigned)(q4 + 8) * 4];
      f32x4 w3 = *(const f32x4*)&wlds[(unsigned)(q4 + 12) * 4];
      ACC4(p0[cur][0], w0[0], w0[1], w0[2], w0[3]);
      ACC4(p0[cur][1], w1[0], w1[1], w1[2], w1[3]);
      ACC4(p0[cur][2], w2[0], w2[1], w2[2], w2[3]);
      ACC4(p0[cur][3], w3[0], w3[1], w3[2], w3[3]);
    }
    if (haveQ1) {
      f32x4 w0 = *(const f32x4*)&wlds[(unsigned)(q4 + 16) * 4];
      f32x4 w1 = *(const f32x4*)&wlds[(unsigned)(q4 + 20) * 4];
      f32x4 w2 = *(const f32x4*)&wlds[(unsigned)(q4 + 24) * 4];
      f32x4 w3 = *(const f32x4*)&wlds[(unsigned)(q4 + 28) * 4];
      ACC4(dq1[0], w0[0], w0[1], w0[2], w0[3]);
      ACC4(dq1[1], w1[0], w1[1], w1[2], w1[3]);
      ACC4(dq1[2], w2[0], w2[1], w2[2], w2[3]);
      ACC4(dq1[3], w3[0], w3[1], w3[2], w3[3]);
    }
    // quarters 2-3 (deg > 32, rare): late-load path
    int e = 32;
#pragma unroll
    for (int i = 2; i < 4; ++i) {
      if (e >= deg) break;
      int bound = min(deg, (i + 1) * 16);
      if (bound - e == 16) {
        int eq = e + q4;
        int s0 = __shfl(src_all, eq);
        int s1 = __shfl(src_all, eq + 4);
        int s2 = __shfl(src_all, eq + 8);
        int s3 = __shfl(src_all, eq + 12);
        f32x4 w0 = *(const f32x4*)&wlds[(unsigned)eq * 4];
        f32x4 w1 = *(const f32x4*)&wlds[(unsigned)(eq + 4) * 4];
        f32x4 w2 = *(const f32x4*)&wlds[(unsigned)(eq + 8) * 4];
        f32x4 w3 = *(const f32x4*)&wlds[(unsigned)(eq + 12) * 4];
        uint4 e0 = *(const uint4*)(hp + ((unsigned)s0 << 8));
        uint4 e1 = *(const uint4*)(hp + ((unsigned)s1 << 8));
        uint4 e2 = *(const uint4*)(hp + ((unsigned)s2 << 8));
        uint4 e3 = *(const uint4*)(hp + ((unsigned)s3 << 8));
        ACC4(e0, w0[0], w0[1], w0[2], w0[3]);
        ACC4(e1, w1[0], w1[1], w1[2], w1[3]);
        ACC4(e2, w2[0], w2[1], w2[2], w2[3]);
        ACC4(e3, w3[0], w3[1], w3[2], w3[3]);
        e += 16;
      } else {
        for (; e < bound; e += 4) {
          int gg = min(4, bound - e);
          int q4e = min(q4, gg - 1);
          int su = __shfl(src_all, e + q4e);
          f32x4 wv4 = *(const f32x4*)&wlds[(unsigned)(e + q4e) * 4];
          if (q4 >= gg) { wv4[0] = 0.f; wv4[1] = 0.f; wv4[2] = 0.f; wv4[3] = 0.f; }
          uint4 d = *(const uint4*)(hp + ((unsigned)su << 8));
          ACC4(d, wv4[0], wv4[1], wv4[2], wv4[3]);
        }
      }
    }
    // ---- normalize + transpose + A16 row write ----
    float dh0 = __shfl(den, 0), dh1 = __shfl(den, 16);
    float dh2 = __shfl(den, 32), dh3 = __shfl(den, 48);
    float i0 = 0.25f / (dh0 + 1e-16f), i1 = 0.25f / (dh1 + 1e-16f);
    float i2 = 0.25f / (dh2 + 1e-16f), i3 = 0.25f / (dh3 + 1e-16f);
    f32x4 v0 = {a[0].x * i0, a[0].y * i0, a[1].x * i0, a[1].y * i0};
    f32x4 v1 = {a[2].x * i1, a[2].y * i1, a[3].x * i1, a[3].y * i1};
    f32x4 v2 = {a[4].x * i2, a[4].y * i2, a[5].x * i2, a[5].y * i2};
    f32x4 v3 = {a[6].x * i3, a[6].y * i3, a[7].x * i3, a[7].y * i3};
    float* wb2 = &redw[(unsigned)lane * 16 + (lane & 7) * 4];
    *(f32x4*)(wb2 + 0) = v0;
    *(f32x4*)(wb2 + 4) = v1;
    *(f32x4*)(wb2 + 8) = v2;
    *(f32x4*)(wb2 + 12) = v3;
    __builtin_amdgcn_wave_barrier();
    int base = (lane & 15) * 16 + (lane & 7) * 4 + (lane >> 4);
    float s = 0.f;
#pragma unroll
    for (int q = 0; q < 4; ++q)
#pragma unroll
      for (int h = 0; h < 4; ++h)
        s += redw[q * 256 + base + 4 * h];
    A16[wv * 4 + nl][lane] = f2b(sigmoidf(s + b1[lane]));
    __builtin_amdgcn_wave_barrier();   // redw reads done before next node writes
  }
#undef PRE_Q0
  __syncthreads();                            // A16 complete; red dead -> ctile ok
  // ---- gemm2: wave wv owns N-tiles 4wv..4wv+3 (head == wv) ----
  int q = lane >> 4, r = lane & 15;
  bf16x8 a0 = *(const bf16x8*)&A16[r][q * 8];
  bf16x8 a1 = *(const bf16x8*)&A16[r][q * 8 + 32];
  f32x4 acc[4] = {};
#pragma unroll
  for (int ntl = 0; ntl < 4; ++ntl) {
    int ntg = wv * 4 + ntl;
    bf16x8 b0 = *(const bf16x8*)&W2b[(((unsigned)ntg * 2 + 0) * 64 + lane) * 8];
    bf16x8 bq = *(const bf16x8*)&W2b[(((unsigned)ntg * 2 + 1) * 64 + lane) * 8];
    acc[ntl] = __builtin_amdgcn_mfma_f32_16x16x32_bf16(a0, b0, acc[ntl], 0, 0, 0);
    acc[ntl] = __builtin_amdgcn_mfma_f32_16x16x32_bf16(a1, bq, acc[ntl], 0, 0, 0);
  }
  // attn dots for head wv
  float ps[4] = {}, pd[4] = {};
#pragma unroll
  for (int i = 0; i < 4; ++i) {
    float sv = as2[wv * 64 + i * 16 + r];
    float dv = ad2[wv * 64 + i * 16 + r];
#pragma unroll
    for (int reg = 0; reg < 4; ++reg) {
      ps[reg] += acc[i][reg] * sv;
      pd[reg] += acc[i][reg] * dv;
    }
  }
#pragma unroll
  for (int reg = 0; reg < 4; ++reg)
#pragma unroll
    for (int o = 1; o < 16; o <<= 1) {
      ps[reg] += __shfl_xor(ps[reg], o);
      pd[reg] += __shfl_xor(pd[reg], o);
    }
  if (r == 0) {
#pragma unroll
    for (int reg = 0; reg < 4; ++reg) {
      int row = blockIdx.x * 16 + q * 4 + reg;
      asrc2[row * 4 + wv] = ps[reg];
      adst2[row * 4 + wv] = pd[reg];
    }
  }
  // pack transposed C8 bytes p = r*16 + ntg through LDS, then coalesced store
#pragma unroll
  for (int reg = 0; reg < 4; ++reg) {
    int rowl = q * 4 + reg;
    int w = __builtin_amdgcn_cvt_pk_fp8_f32(acc[0][reg], acc[1][reg], 0, false);
    w = __builtin_amdgcn_cvt_pk_fp8_f32(acc[2][reg], acc[3][reg], w, true);
    sm.ctile[rowl * 64 + r * 4 + wv] = (unsigned)w;
  }
  __syncthreads();
  int row = threadIdx.x >> 4, seg = threadIdx.x & 15;
  uint4 v = *(const uint4*)&sm.ctile[row * 64 + seg * 4];
  *(uint4*)(h8b + ((size_t)(blockIdx.x * 16 + row)) * 256 + (unsigned)seg * 16) = v;
}

// ------- aggregation layer 2 (R26 core, writes bf16 out rows) -------------------
__global__ void aggregate_kernel(const unsigned char* __restrict__ h8,
                                 const float* __restrict__ asrc,
                                 const float* __restrict__ adst,
                                 const int* __restrict__ cnt,
                                 const unsigned short* __restrict__ csr_src,
                                 const float* __restrict__ bias,
                                 unsigned short* __restrict__ outb) {
  int wave = threadIdx.x >> 6, lane = threadIdx.x & 63;
  int node = blockIdx.x * 4 + wave;              // NN % 4 == 0: always valid
  __shared__ float wtab[4][256];
  __shared__ float red[4][1056];
  float s = agg_node(node, lane, wtab[wave], red[wave], h8, asrc, adst, cnt, csr_src);
  float ov = sigmoidf(s + bias[lane]);
  outb[(size_t)node * 64 + lane] = f2b(ov);     // 128B/wave coalesced
}

// ------- pool partial with FUSED gate MFMA (per-block, own chunk nodes) ----------
__global__ void pool_partial_kernel(const int* __restrict__ goffs,
                                    const unsigned short* __restrict__ out2b,
                                    const unsigned short* __restrict__ Bg,
                                    const float* __restrict__ gb1,
                                    const float* __restrict__ gamma,
                                    const float* __restrict__ beta,
                                    const float* __restrict__ gw2,
                                    const float* __restrict__ gb2,
                                    float* __restrict__ part_acc,
                                    float* __restrict__ part_den) {
  int b = blockIdx.x, j = blockIdx.y;
  int beg = goffs[b], end = goffs[b + 1];
  int chunk = (end - beg + CH - 1) / CH;
  int cb = beg + j * chunk;
  int ce = min(end, cb + chunk);
  int lane = threadIdx.x & 63, wave = threadIdx.x >> 6;
  int q = lane >> 4, r = lane & 15;
  const float s = rsqrtf(1.f + 1e-5f);
  float gb2v = gb2[0];
  float accv = 0.f, den = 0.f;
  for (int n0 = cb + wave * 16; n0 < ce; n0 += 64) {
    // gate MFMA for nodes n0..n0+15
    f32x4 acc[4] = {};
    int row = n0 + r;
    if (row >= NN) row = NN - 1;
    const unsigned short* Arow = out2b + (size_t)row * 64 + q * 8;
#pragma unroll
    for (int kc = 0; kc < 2; ++kc) {
      bf16x8 a = *(const bf16x8*)(Arow + kc * 32);
#pragma unroll
      for (int nt = 0; nt < 4; ++nt) {
        bf16x8 b8 = *(const bf16x8*)&Bg[(((size_t)nt * 2 + kc) * 64 + lane) * 8];
        acc[nt] = __builtin_amdgcn_mfma_f32_16x16x32_bf16(a, b8, acc[nt], 0, 0, 0);
      }
    }
    float sum[4] = {0.f, 0.f, 0.f, 0.f};
#pragma unroll
    for (int nt = 0; nt < 4; ++nt) {
      int col = nt * 16 + r;
      float off = gb1[col] * gamma[col] * s + beta[col];
      float w2 = gw2[col];
#pragma unroll
      for (int reg = 0; reg < 4; ++reg)
        sum[reg] += fmaxf(acc[nt][reg] + off, 0.f) * w2;
    }
#pragma unroll
    for (int reg = 0; reg < 4; ++reg)
#pragma unroll
      for (int o = 1; o < 16; o <<= 1) sum[reg] += __shfl_xor(sum[reg], o);
    float gx[4];
#pragma unroll
    for (int reg = 0; reg < 4; ++reg) {
      int n = n0 + q * 4 + reg;
      gx[reg] = (n < ce) ? __expf(sum[reg] + gb2v) : 0.f;
    }
#pragma unroll
    for (int t = 0; t < 16; ++t) {
      int n = n0 + t;
      if (n >= ce) break;
      float gv = __shfl(gx[t & 3], (t >> 2) << 4);
      accv += gv * b2f(out2b[(size_t)n * 64 + lane]);
      den += gv;  // identical on all lanes
    }
  }
  __shared__ float sacc[4][64];
  __shared__ float sden[4];
  sacc[wave][lane] = accv;
  if (lane == 0) sden[wave] = den;
  __syncthreads();
  if (wave == 0) {
    float a = sacc[0][lane] + sacc[1][lane] + sacc[2][lane] + sacc[3][lane];
    part_acc[((size_t)b * CH + j) * 64 + lane] = a;
    if (lane == 0) part_den[b * CH + j] = sden[0] + sden[1] + sden[2] + sden[3];
  }
}

__global__ void pool_final_kernel(const float* __restrict__ part_acc,
                                  const float* __restrict__ part_den,
                                  const float* __restrict__ lw, const float* __restrict__ lb,
                                  float* __restrict__ out) {
  int b = blockIdx.x, lane = threadIdx.x;  // 64 threads
  float a = 0.f;
#pragma unroll
  for (int j = 0; j < CH; ++j) a += part_acc[((size_t)b * CH + j) * 64 + lane];
  float den = (lane < CH) ? part_den[b * CH + lane] : 0.f;
  den = wred(den);
  den = __shfl(den, 0);
  float p = a / (den + 1e-16f);
  float v = wred(p * lw[lane]);
  if (lane == 0) out[b] = sigmoidf(v + lb[0]);
}

extern "C" void kernel_launch(void* const* d_in, const int* in_sizes, int n_in,
                              void* d_out, int out_size, void* d_ws, size_t ws_size,
                              hipStream_t stream) {
  const float* x    = (const float*)d_in[0];
  const int*   ei   = (const int*)d_in[1];
  const int*   batch= (const int*)d_in[2];
  const float* W1   = (const float*)d_in[4];
  const float* as1  = (const float*)d_in[5];
  const float* ad1  = (const float*)d_in[6];
  const float* b1   = (const float*)d_in[7];
  const float* W2   = (const float*)d_in[8];
  const float* as2  = (const float*)d_in[9];
  const float* ad2  = (const float*)d_in[10];
  const float* b2   = (const float*)d_in[11];
  const float* gw1  = (const float*)d_in[12];
  const float* gb1  = (const float*)d_in[13];
  const float* gamma= (const float*)d_in[14];
  const float* beta = (const float*)d_in[15];
  const float* gw2  = (const float*)d_in[16];
  const float* gb2  = (const float*)d_in[17];
  const float* lw   = (const float*)d_in[18];
  const float* lb   = (const float*)d_in[19];
  float* out = (float*)d_out;

  char* ws = (char*)d_ws;
  size_t off = 0;
  auto alloc = [&](size_t bytes) -> void* {
    void* p = ws + off;
    off = (off + bytes + 255) & ~(size_t)255;
    return p;
  };
  unsigned short* W1b    = (unsigned short*)alloc((size_t)128 * 256 * 2);
  unsigned short* W2b    = (unsigned short*)alloc((size_t)64 * 256 * 2);
  unsigned short* Bg     = (unsigned short*)alloc((size_t)64 * 64 * 2);
  unsigned char*  h8     = (unsigned char*)alloc((size_t)NN * 256);
  unsigned char*  h8b    = (unsigned char*)alloc((size_t)NN * 256);
  unsigned short* out2b  = (unsigned short*)alloc((size_t)NN * 64 * 2);
  float*    asrc    = (float*)alloc((size_t)NN * 4 * 4);
  float*    adst    = (float*)alloc((size_t)NN * 4 * 4);
  float*    asrc2   = (float*)alloc((size_t)NN * 4 * 4);
  float*    adst2   = (float*)alloc((size_t)NN * 4 * 4);
  int*      cnt     = (int*)alloc((size_t)NN * 4);
  unsigned short* csr16 = (unsigned short*)alloc((size_t)NN * SLOTS * 2);
  unsigned* bins    = (unsigned*)alloc((size_t)EBN * NBKT * CAP * 4);
  int*      binCnt  = (int*)alloc((size_t)EBN * NBKT * 4);
  int*      ovf_cnt = (int*)alloc(256);
  unsigned* ovf     = (unsigned*)alloc((size_t)OVFCAP * 4);
  int*      goffs   = (int*)alloc((size_t)(NG + 1) * 4);
  float*    pacc    = (float*)alloc((size_t)NG * CH * 64 * 4);
  float*    pden    = (float*)alloc((size_t)NG * CH * 4);

  // prep: packs + bounds + ovf zero
  prep_kernel<<<209, 256, 0, stream>>>(W1, W2, gw1, gamma, batch,
                                       W1b, W2b, Bg, goffs, ovf_cnt);

  // Layer 1 GEMM + atomic-free bucket histogram (pass A) overlapped in one launch
  gemm1_build_kernel<<<GB + EBN, 256, 0, stream>>>(x, W1b, h8, as1, ad1, asrc, adst,
                                                   ei, bins, binCnt, ovf_cnt, ovf);
  // pass C: finalize csr + cnt per bucket (plain stores, LDS ranks)
  csr_build_kernel<<<NBKT, 1024, 0, stream>>>(bins, binCnt, ovf_cnt, ovf, csr16, cnt);

  // FUSED aggregate1 + gemm2 + attn2 (16 nodes, q0 cross-node prefetch)
  agg1_gemm2_kernel<<<MT, 256, 0, stream>>>(h8, asrc, adst, cnt, csr16, b1,
                                            W2b, as2, ad2, h8b, asrc2, adst2);

  // Layer 2 aggregation
  aggregate_kernel<<<NN / 4, 256, 0, stream>>>(h8b, asrc2, adst2, cnt, csr16, b2, out2b);

  // Global attention pooling (gate MFMA fused into partial)
  pool_partial_kernel<<<dim3(NG, CH), 256, 0, stream>>>(goffs, out2b, Bg, gb1, gamma, beta,
                                                        gw2, gb2, pacc, pden);
  pool_final_kernel<<<NG, 64, 0, stream>>>(pacc, pden, lw, lb, out);
}

// Round 12
// 227.049 us; speedup vs baseline: 1.1605x; 1.0380x over previous
//
#include <hip/hip_runtime.h>

// GAT forward (2x GATConv + GlobalAttention pool) for MI355X.
// R29 = EXACT REVERT to R26 (best measured, 231.7us). Cross-node prefetch line
// closed: R27 (spilled, 263.5) and R28 (spill-free via launch_bounds, 235.7)
// both lost to R26's simple intra-node hoist -> aggregate gather is at its
// concurrency floor (~2 TB/s on the structural 8-XCD x 12.8MB h8 re-fetch,
// 94MB FETCH). R26 structure:
//   - h8 gathers for slots 0-15 (always) and 16-31 (wave-uniform if deg>16)
//     issued BEFORE the weight phase with shfl index clamped to min(slot,deg-1);
//     wlds written unconditionally (0 for invalid) so clamped rows annihilate.
//   - agg1+gemm2+attn2 fused (16 nodes/block); atomic-free CSR build; LDS-staged
//     GEMM B; transposed fp8 C8; LDS weight table aggregate. 7 launches.

constexpr int NN = 50000;          // nodes
constexpr int EE = 800000;         // edges (without self loops)
constexpr int NG = 64;             // graphs
constexpr float NEG = 0.2f;       // leaky relu slope
constexpr int MT = NN / 16;        // 3125 m-tiles (NN % 16 == 0)
constexpr int SLOTS = 64;          // CSR slots per node; P(deg>64) ~ 0 (Poisson(16)+1)
constexpr int CH = 16;             // pool chunks per graph
constexpr int GB = (MT + 3) / 4;   // gemm blocks (wave per m-tile, 4 waves/block)

constexpr int EB_EDGES = 4096;                     // edges per hist block
constexpr int EBN = (EE + EB_EDGES - 1) / EB_EDGES; // 196 hist blocks
constexpr int NBKT = (NN + 255) / 256;             // 196 coarse buckets (dst>>8)
constexpr int CAP = 48;            // bin capacity; Poisson(20.9), P(>48)*bins ~ 0.1
constexpr int OVFCAP = 8192;       // overflow fallback list

static_assert(NN % 16 == 0, "fused block = 16 nodes");

using bf16x8 = __attribute__((ext_vector_type(8))) __bf16;
using f32x4  = __attribute__((ext_vector_type(4))) float;
using f32x2  = __attribute__((ext_vector_type(2))) float;

__device__ __forceinline__ float wred(float v) {
#pragma unroll
  for (int o = 32; o; o >>= 1) v += __shfl_down(v, o);
  return v;
}
__device__ __forceinline__ float sigmoidf(float v) { return 1.f / (1.f + __expf(-v)); }
__device__ __forceinline__ float lrelu(float v) { return fmaxf(v, NEG * v); }
__device__ __forceinline__ unsigned short f2b(float f) {
  union { float f; unsigned u; } v; v.f = f;
  unsigned r = v.u + 0x7fff + ((v.u >> 16) & 1);
  return (unsigned short)(r >> 16);
}
__device__ __forceinline__ float b2f(unsigned short b) {
  union { unsigned u; float f; } v; v.u = ((unsigned)b) << 16;
  return v.f;
}

// ------- prep: pack W1/W2/gateW + graph bounds + zero ovf counter ---------------
__global__ void prep_kernel(const float* __restrict__ W1, const float* __restrict__ W2,
                            const float* __restrict__ gw1, const float* __restrict__ gamma,
                            const int* __restrict__ batch,
                            unsigned short* __restrict__ W1b, unsigned short* __restrict__ W2b,
                            unsigned short* __restrict__ Bg, int* __restrict__ goffs,
                            int* __restrict__ ovf_cnt) {
  int b = blockIdx.x;
  if (b < 128) {  // W1 pack: K=128, KC=4, N=256
    int idx = b * 256 + threadIdx.x;
    int j = idx & 7, lane = (idx >> 3) & 63, rest = idx >> 9;
    int kc = rest & 3, ntile = rest >> 2;
    W1b[idx] = f2b(W1[(kc * 32 + (lane >> 4) * 8 + j) * 256 + ntile * 16 + (lane & 15)]);
    return;
  }
  if (b < 192) {  // W2 pack: K=64, KC=2, N=256
    int idx = (b - 128) * 256 + threadIdx.x;
    int j = idx & 7, lane = (idx >> 3) & 63, rest = idx >> 9;
    int kc = rest & 1, ntile = rest >> 1;
    W2b[idx] = f2b(W2[(kc * 32 + (lane >> 4) * 8 + j) * 256 + ntile * 16 + (lane & 15)]);
    return;
  }
  if (b < 208) {  // gate W pack: K=64, KC=2, N=64, BN scale folded
    int idx = (b - 192) * 256 + threadIdx.x;  // 0..4095
    int j = idx & 7, lane = (idx >> 3) & 63, rest = idx >> 9;
    int kc = rest & 1, nt = rest >> 1;
    int k = kc * 32 + (lane >> 4) * 8 + j;
    int n = nt * 16 + (lane & 15);
    Bg[idx] = f2b(gw1[k * 64 + n] * gamma[n] * rsqrtf(1.f + 1e-5f));
    return;
  }
  // graph bounds (sorted batch, binary search) + ovf counter zero
  if (threadIdx.x == 0) *ovf_cnt = 0;
  int g = threadIdx.x;
  if (g <= NG) {
    int lo = 0, hi = NN;
    while (lo < hi) {
      int mid = (lo + hi) >> 1;
      if (batch[mid] < g) lo = mid + 1; else hi = mid;
    }
    goffs[g] = lo;
  }
}

// ------- MFMA GEMM body: A in regs, B in LDS, fused attn, TRANSPOSED fp8 C ------
template <int KC>
__device__ __forceinline__ void gemm_body(int mt, int lane, const bf16x8* av,
                                          const unsigned short* Bp,  // LDS
                                          unsigned char* __restrict__ C8,
                                          const float* __restrict__ att_s,
                                          const float* __restrict__ att_d,
                                          float* __restrict__ asrc,
                                          float* __restrict__ adst) {
  int m0 = mt * 16;
  int q = lane >> 4, r = lane & 15;
  f32x4 acc[16] = {};
#pragma unroll
  for (int kc = 0; kc < KC; ++kc) {
#pragma unroll
    for (int nt = 0; nt < 16; ++nt) {
      bf16x8 b = *(const bf16x8*)&Bp[(((unsigned)nt * KC + kc) * 64 + lane) * 8];
      acc[nt] = __builtin_amdgcn_mfma_f32_16x16x32_bf16(av[kc], b, acc[nt], 0, 0, 0);
    }
  }
  // transposed C8 store: byte p = r*16 + nt  (true channel c = nt*16 + r)
#pragma unroll
  for (int reg = 0; reg < 4; ++reg) {
    unsigned row = m0 + q * 4 + reg;
    uint4 pk;
    int w;
    w = __builtin_amdgcn_cvt_pk_fp8_f32(acc[0][reg], acc[1][reg], 0, false);
    w = __builtin_amdgcn_cvt_pk_fp8_f32(acc[2][reg], acc[3][reg], w, true);
    pk.x = (unsigned)w;
    w = __builtin_amdgcn_cvt_pk_fp8_f32(acc[4][reg], acc[5][reg], 0, false);
    w = __builtin_amdgcn_cvt_pk_fp8_f32(acc[6][reg], acc[7][reg], w, true);
    pk.y = (unsigned)w;
    w = __builtin_amdgcn_cvt_pk_fp8_f32(acc[8][reg], acc[9][reg], 0, false);
    w = __builtin_amdgcn_cvt_pk_fp8_f32(acc[10][reg], acc[11][reg], w, true);
    pk.z = (unsigned)w;
    w = __builtin_amdgcn_cvt_pk_fp8_f32(acc[12][reg], acc[13][reg], 0, false);
    w = __builtin_amdgcn_cvt_pk_fp8_f32(acc[14][reg], acc[15][reg], w, true);
    pk.w = (unsigned)w;
    *(uint4*)(C8 + (size_t)row * 256 + (unsigned)r * 16) = pk;
  }
  // fused attention dots (true-channel order)
  float ps[4][4] = {}, pd[4][4] = {};
#pragma unroll
  for (int head = 0; head < 4; ++head) {
#pragma unroll
    for (int i = 0; i < 4; ++i) {
      float sv = att_s[head * 64 + i * 16 + r];
      float dv = att_d[head * 64 + i * 16 + r];
#pragma unroll
      for (int reg = 0; reg < 4; ++reg) {
        ps[head][reg] += acc[head * 4 + i][reg] * sv;
        pd[head][reg] += acc[head * 4 + i][reg] * dv;
      }
    }
  }
#pragma unroll
  for (int head = 0; head < 4; ++head)
#pragma unroll
    for (int reg = 0; reg < 4; ++reg)
#pragma unroll
      for (int o = 1; o < 16; o <<= 1) {
        ps[head][reg] += __shfl_xor(ps[head][reg], o);
        pd[head][reg] += __shfl_xor(pd[head][reg], o);
      }
  if (r == 0) {
#pragma unroll
    for (int reg = 0; reg < 4; ++reg) {
      int row = m0 + q * 4 + reg;
#pragma unroll
      for (int head = 0; head < 4; ++head) {
        asrc[row * 4 + head] = ps[head][reg];
        adst[row * 4 + head] = pd[head][reg];
      }
    }
  }
}

// ------- GEMM1 (LDS-staged B) + atomic-free bucket-histogram pass A -------------
__global__ void gemm1_build_kernel(const float* __restrict__ x,
                                   const unsigned short* __restrict__ W1b,
                                   unsigned char* __restrict__ C8,
                                   const float* __restrict__ att_s,
                                   const float* __restrict__ att_d,
                                   float* __restrict__ asrc, float* __restrict__ adst,
                                   const int* __restrict__ ei,
                                   unsigned* __restrict__ bins,
                                   int* __restrict__ binCnt,
                                   int* __restrict__ ovf_cnt,
                                   unsigned* __restrict__ ovf) {
  __shared__ union {
    unsigned short B[128 * 256];   // 64 KB staged W1b
    int hist[NBKT];
  } smem;
  int b = blockIdx.x;
  if (b < GB) {
    int wave = threadIdx.x >> 6, lane = threadIdx.x & 63;
    int mt0 = b * 4 + wave;
    int mt = min(mt0, MT - 1);      // tail waves load safe addr, exit after barrier
    int q = lane >> 4, r = lane & 15;
    // stage B (all 256 threads; 16 x uint4 each)
#pragma unroll
    for (int it = 0; it < 16; ++it)
      ((uint4*)smem.B)[it * 256 + threadIdx.x] = ((const uint4*)W1b)[it * 256 + threadIdx.x];
    // hoisted A load + bf16 convert (overlaps staging; barrier drains all)
    bf16x8 av[4];
    {
      const float* Arow = x + (size_t)(mt * 16 + r) * 128 + q * 8;
      float4 f0[4], f1[4];
#pragma unroll
      for (int kc = 0; kc < 4; ++kc) {
        f0[kc] = *(const float4*)(Arow + kc * 32);
        f1[kc] = *(const float4*)(Arow + kc * 32 + 4);
      }
#pragma unroll
      for (int kc = 0; kc < 4; ++kc) {
        union { bf16x8 v; unsigned short s[8]; } u;
        u.s[0] = f2b(f0[kc].x); u.s[1] = f2b(f0[kc].y);
        u.s[2] = f2b(f0[kc].z); u.s[3] = f2b(f0[kc].w);
        u.s[4] = f2b(f1[kc].x); u.s[5] = f2b(f1[kc].y);
        u.s[6] = f2b(f1[kc].z); u.s[7] = f2b(f1[kc].w);
        av[kc] = u.v;
      }
    }
    __syncthreads();
    if (mt0 >= MT) return;
    gemm_body<4>(mt, lane, av, smem.B, C8, att_s, att_d, asrc, adst);
    return;
  }
  // pass A: per-block LDS histogram over coarse buckets, LDS ranks, bin scatter
  int hb = b - GB;
  for (int t = threadIdx.x; t < NBKT; t += 256) smem.hist[t] = 0;
  __syncthreads();
  int e0 = hb * EB_EDGES + threadIdx.x * 16;
#pragma unroll
  for (int k4 = 0; k4 < 4; ++k4) {
    int e = e0 + k4 * 4;
    if (e >= EE) break;
    int4 s4 = *(const int4*)&ei[e];
    int4 d4 = *(const int4*)&ei[EE + e];
    int ss[4] = {s4.x, s4.y, s4.z, s4.w};
    int dd[4] = {d4.x, d4.y, d4.z, d4.w};
#pragma unroll
    for (int u = 0; u < 4; ++u) {
      if (e + u >= EE) break;
      int src = ss[u], dst = dd[u];
      int bkt = dst >> 8;
      int rr = atomicAdd(&smem.hist[bkt], 1);   // LDS atomic — stays in the CU
      if (rr < CAP) {
        bins[((unsigned)hb * NBKT + bkt) * CAP + rr] =
            (unsigned)src | ((unsigned)(dst & 255) << 16);
      } else {  // statistically ~never; bulletproof fallback
        int o = atomicAdd(ovf_cnt, 1);
        if (o < OVFCAP) ovf[o] = (unsigned)src | ((unsigned)dst << 16);
      }
    }
  }
  __syncthreads();
  for (int t = threadIdx.x; t < NBKT; t += 256) binCnt[hb * NBKT + t] = smem.hist[t];
}

// ------- pass C: per-bucket CSR finalization (plain stores, LDS ranks) ----------
__global__ __launch_bounds__(1024) void csr_build_kernel(
    const unsigned* __restrict__ bins, const int* __restrict__ binCnt,
    const int* __restrict__ ovf_cnt, const unsigned* __restrict__ ovf,
    unsigned short* __restrict__ csr16, int* __restrict__ cnt) {
  int b = blockIdx.x;                 // bucket = nodes [b*256, b*256+256)
  __shared__ int hist[256];
  int t = threadIdx.x;
  int node0 = b << 8;
  if (t < 256) {
    hist[t] = 1;                      // slot 0 reserved for the self loop
    int node = node0 + t;
    if (node < NN) csr16[(unsigned)node * SLOTS] = (unsigned short)node;
  }
  __syncthreads();
  int wave = t >> 6, lane = t & 63;
  for (int i = wave; i < EBN; i += 16) {
    int c = binCnt[i * NBKT + b];
    if (c > CAP) c = CAP;
    for (int base = 0; base < c; base += 64) {
      int j = base + lane;
      if (j < c) {
        unsigned p = bins[((unsigned)i * NBKT + b) * CAP + j];
        int dl = p >> 16, src = p & 0xffff;
        int r = atomicAdd(&hist[dl], 1);
        if (r < SLOTS) csr16[(unsigned)(node0 + dl) * SLOTS + r] = (unsigned short)src;
      }
    }
  }
  __syncthreads();
  int oc = *ovf_cnt;
  if (oc > OVFCAP) oc = OVFCAP;
  for (int j = t; j < oc; j += 1024) {
    unsigned p = ovf[j];
    int dst = (int)(p >> 16);
    if ((dst >> 8) == b) {
      int r = atomicAdd(&hist[dst & 255], 1);
      if (r < SLOTS) csr16[(unsigned)dst * SLOTS + r] = (unsigned short)(p & 0xffff);
    }
  }
  __syncthreads();
  if (t < 256) {
    int node = node0 + t;
    if (node < NN) cnt[node] = hist[t];
  }
}

// ------- aggregate core for ONE node on ONE wave (hoisted gathers) --------------
// returns per-channel (oc = lane) normalized head-mean sum for this node.
__device__ __forceinline__ float agg_node(int node, int lane,
                                          float* __restrict__ wlds,   // [256] per wave
                                          float* __restrict__ redw,   // [1056] per wave
                                          const unsigned char* __restrict__ h8,
                                          const float* __restrict__ asrc,
                                          const float* __restrict__ adst,
                                          const int* __restrict__ cnt,
                                          const unsigned short* __restrict__ csr_src) {
  int q4 = lane >> 4, r16 = lane & 15, hgrp = q4;
  int deg = min(cnt[node], SLOTS);
  float adh = adst[node * 4 + hgrp];
  int src_all = csr_src[(unsigned)node * SLOTS + lane];  // coalesced 128B load
  int dm1 = deg - 1;                                     // deg >= 1 (self loop)
  const unsigned char* hp = h8 + (unsigned)r16 * 16;
  // ---- hoisted h8 gathers (slots 0-15 always; 16-31 if deg>16), clamped ----
  // weight=0 is written unconditionally for invalid slots, so clamped rows
  // are annihilated in the accumulate. Overlaps with the weight phase below.
  uint4 d0, d1, d2, d3, d4, d5, d6, d7;
  {
    int s0 = __shfl(src_all, min(q4, dm1));
    int s1 = __shfl(src_all, min(q4 + 4, dm1));
    int s2 = __shfl(src_all, min(q4 + 8, dm1));
    int s3 = __shfl(src_all, min(q4 + 12, dm1));
    d0 = *(const uint4*)(hp + ((unsigned)s0 << 8));
    d1 = *(const uint4*)(hp + ((unsigned)s1 << 8));
    d2 = *(const uint4*)(hp + ((unsigned)s2 << 8));
    d3 = *(const uint4*)(hp + ((unsigned)s3 << 8));
  }
  bool haveQ1 = deg > 16;                               // wave-uniform
  if (haveQ1) {
    int s4 = __shfl(src_all, min(q4 + 16, dm1));
    int s5 = __shfl(src_all, min(q4 + 20, dm1));
    int s6 = __shfl(src_all, min(q4 + 24, dm1));
    int s7 = __shfl(src_all, min(q4 + 28, dm1));
    d4 = *(const uint4*)(hp + ((unsigned)s4 << 8));
    d5 = *(const uint4*)(hp + ((unsigned)s5 << 8));
    d6 = *(const uint4*)(hp + ((unsigned)s6 << 8));
    d7 = *(const uint4*)(hp + ((unsigned)s7 << 8));
  }
  // ---- weight phase (executes while the gathers are in flight) ----
  float den = 0.f;
#pragma unroll
  for (int i = 0; i < 4; ++i) {
    int slot = i * 16 + r16;
    float w = 0.f;
    if (i * 16 < deg) {                          // wave-uniform skip (deg~17)
      int s = __shfl(src_all, slot);
      bool valid = slot < deg;
      float xv = asrc[(unsigned)(valid ? s : 0) * 4 + hgrp];
      w = valid ? __expf(lrelu(xv + adh)) : 0.f;
    }
    wlds[slot * 4 + hgrp] = w;                   // ALWAYS written (0 if invalid)
    den += w;
  }
#pragma unroll
  for (int o = 1; o < 16; o <<= 1) den += __shfl_xor(den, o);  // den per head hgrp
  __builtin_amdgcn_wave_barrier();               // keep write->read order (intra-wave)

  f32x2 a[8] = {};
#define ACC4(d, wA, wB, wC, wD)                                              \
  {                                                                          \
    a[0] += __builtin_amdgcn_cvt_pk_f32_fp8((d).x, false) * (wA);            \
    a[1] += __builtin_amdgcn_cvt_pk_f32_fp8((d).x, true) * (wA);             \
    a[2] += __builtin_amdgcn_cvt_pk_f32_fp8((d).y, false) * (wB);            \
    a[3] += __builtin_amdgcn_cvt_pk_f32_fp8((d).y, true) * (wB);             \
    a[4] += __builtin_amdgcn_cvt_pk_f32_fp8((d).z, false) * (wC);            \
    a[5] += __builtin_amdgcn_cvt_pk_f32_fp8((d).z, true) * (wC);             \
    a[6] += __builtin_amdgcn_cvt_pk_f32_fp8((d).w, false) * (wD);            \
    a[7] += __builtin_amdgcn_cvt_pk_f32_fp8((d).w, true) * (wD);             \
  }
  // quarter 0 (slots 0-15), preloaded
  {
    f32x4 w0 = *(const f32x4*)&wlds[(unsigned)q4 * 4];
    f32x4 w1 = *(const f32x4*)&wlds[(unsigned)(q4 + 4) * 4];
    f32x4 w2 = *(const f32x4*)&wlds[(unsigned)(q4 + 8) * 4];
    f32x4 w3 = *(const f32x4*)&wlds[(unsigned)(q4 + 12) * 4];
    ACC4(d0, w0[0], w0[1], w0[2], w0[3]);
    ACC4(d1, w1[0], w1[1], w1[2], w1[3]);
    ACC4(d2, w2[0], w2[1], w2[2], w2[3]);
    ACC4(d3, w3[0], w3[1], w3[2], w3[3]);
  }
  // quarter 1 (slots 16-31), preloaded
  if (haveQ1) {
    f32x4 w0 = *(const f32x4*)&wlds[(unsigned)(q4 + 16) * 4];
    f32x4 w1 = *(const f32x4*)&wlds[(unsigned)(q4 + 20) * 4];
    f32x4 w2 = *(const f32x4*)&wlds[(unsigned)(q4 + 24) * 4];
    f32x4 w3 = *(const f32x4*)&wlds[(unsigned)(q4 + 28) * 4];
    ACC4(d4, w0[0], w0[1], w0[2], w0[3]);
    ACC4(d5, w1[0], w1[1], w1[2], w1[3]);
    ACC4(d6, w2[0], w2[1], w2[2], w2[3]);
    ACC4(d7, w3[0], w3[1], w3[2], w3[3]);
  }
  // quarters 2-3 (deg > 32, rare): original late-load path
  int e = 32;
#pragma unroll
  for (int i = 2; i < 4; ++i) {
    if (e >= deg) break;
    int bound = min(deg, (i + 1) * 16);
    if (bound - e == 16) {       // full quarter: 4 edges/lane-group
      int eq = e + q4;
      int s0 = __shfl(src_all, eq);
      int s1 = __shfl(src_all, eq + 4);
      int s2 = __shfl(src_all, eq + 8);
      int s3 = __shfl(src_all, eq + 12);
      f32x4 w0 = *(const f32x4*)&wlds[(unsigned)eq * 4];          // broadcast x16
      f32x4 w1 = *(const f32x4*)&wlds[(unsigned)(eq + 4) * 4];
      f32x4 w2 = *(const f32x4*)&wlds[(unsigned)(eq + 8) * 4];
      f32x4 w3 = *(const f32x4*)&wlds[(unsigned)(eq + 12) * 4];
      uint4 e0 = *(const uint4*)(hp + ((unsigned)s0 << 8));
      uint4 e1 = *(const uint4*)(hp + ((unsigned)s1 << 8));
      uint4 e2 = *(const uint4*)(hp + ((unsigned)s2 << 8));
      uint4 e3 = *(const uint4*)(hp + ((unsigned)s3 << 8));
      ACC4(e0, w0[0], w0[1], w0[2], w0[3]);
      ACC4(e1, w1[0], w1[1], w1[2], w1[3]);
      ACC4(e2, w2[0], w2[1], w2[2], w2[3]);
      ACC4(e3, w3[0], w3[1], w3[2], w3[3]);
      e += 16;
    } else {                      // tail quarter (<16 edges), masked groups
      for (; e < bound; e += 4) {
        int gg = min(4, bound - e);
        int q4e = min(q4, gg - 1);
        int su = __shfl(src_all, e + q4e);
        f32x4 wv = *(const f32x4*)&wlds[(unsigned)(e + q4e) * 4];
        if (q4 >= gg) { wv[0] = 0.f; wv[1] = 0.f; wv[2] = 0.f; wv[3] = 0.f; }
        uint4 d = *(const uint4*)(hp + ((unsigned)su << 8));
        ACC4(d, wv[0], wv[1], wv[2], wv[3]);
      }
    }
  }
#undef ACC4
  // per-head normalize (0.25 = head-mean folded), then LDS transpose
  float dh0 = __shfl(den, 0), dh1 = __shfl(den, 16);
  float dh2 = __shfl(den, 32), dh3 = __shfl(den, 48);
  float i0 = 0.25f / (dh0 + 1e-16f), i1 = 0.25f / (dh1 + 1e-16f);
  float i2 = 0.25f / (dh2 + 1e-16f), i3 = 0.25f / (dh3 + 1e-16f);
  f32x4 v0 = {a[0].x * i0, a[0].y * i0, a[1].x * i0, a[1].y * i0};
  f32x4 v1 = {a[2].x * i1, a[2].y * i1, a[3].x * i1, a[3].y * i1};
  f32x4 v2 = {a[4].x * i2, a[4].y * i2, a[5].x * i2, a[5].y * i2};
  f32x4 v3 = {a[6].x * i3, a[6].y * i3, a[7].x * i3, a[7].y * i3};
  // bank-swizzled transpose: producer lane L at float offset L*16 + (L&7)*4
  float* wb2 = &redw[(unsigned)lane * 16 + (lane & 7) * 4];
  *(f32x4*)(wb2 + 0) = v0;
  *(f32x4*)(wb2 + 4) = v1;
  *(f32x4*)(wb2 + 8) = v2;
  *(f32x4*)(wb2 + 12) = v3;
  __builtin_amdgcn_wave_barrier();
  // reader: out channel oc=lane sums true ch 64h+oc over 4 heads x 4 q-partials;
  // producer lane' = q*16 + (oc&15), value t = 4h + (oc>>4)
  int base = (lane & 15) * 16 + (lane & 7) * 4 + (lane >> 4);
  float s = 0.f;
#pragma unroll
  for (int q = 0; q < 4; ++q)
#pragma unroll
    for (int h = 0; h < 4; ++h)
      s += redw[q * 256 + base + 4 * h];
  return s;
}

// ------- FUSED aggregate1 + gemm2 + attn2: block = 16 nodes ---------------------
__global__ void agg1_gemm2_kernel(const unsigned char* __restrict__ h8,
                                  const float* __restrict__ asrc1,
                                  const float* __restrict__ adst1,
                                  const int* __restrict__ cnt,
                                  const unsigned short* __restrict__ csr_src,
                                  const float* __restrict__ b1,
                                  const unsigned short* __restrict__ W2b,
                                  const float* __restrict__ as2,
                                  const float* __restrict__ ad2,
                                  unsigned char* __restrict__ h8b,
                                  float* __restrict__ asrc2,
                                  float* __restrict__ adst2) {
  int wv = threadIdx.x >> 6, lane = threadIdx.x & 63;
  __shared__ float wtab[4][256];
  __shared__ union { float red[4][1056]; unsigned ctile[16 * 64]; } sm;
  __shared__ unsigned short A16[16][72];     // out1 tile, +8 pad per row
  // ---- aggregate layer 1: 4 sequential nodes per wave -> A16 rows ----
  for (int nl = 0; nl < 4; ++nl) {
    int rl = wv * 4 + nl;
    int node = blockIdx.x * 16 + rl;
    float s = agg_node(node, lane, wtab[wv], sm.red[wv], h8, asrc1, adst1, cnt, csr_src);
    A16[rl][lane] = f2b(sigmoidf(s + b1[lane]));
  }
  __syncthreads();                            // A16 complete; red dead -> ctile ok
  // ---- gemm2: wave wv owns N-tiles 4wv..4wv+3 (head == wv) ----
  int q = lane >> 4, r = lane & 15;
  bf16x8 a0 = *(const bf16x8*)&A16[r][q * 8];
  bf16x8 a1 = *(const bf16x8*)&A16[r][q * 8 + 32];
  f32x4 acc[4] = {};
#pragma unroll
  for (int ntl = 0; ntl < 4; ++ntl) {
    int ntg = wv * 4 + ntl;
    bf16x8 b0 = *(const bf16x8*)&W2b[(((unsigned)ntg * 2 + 0) * 64 + lane) * 8];
    bf16x8 bq = *(const bf16x8*)&W2b[(((unsigned)ntg * 2 + 1) * 64 + lane) * 8];
    acc[ntl] = __builtin_amdgcn_mfma_f32_16x16x32_bf16(a0, b0, acc[ntl], 0, 0, 0);
    acc[ntl] = __builtin_amdgcn_mfma_f32_16x16x32_bf16(a1, bq, acc[ntl], 0, 0, 0);
  }
  // attn dots for head wv
  float ps[4] = {}, pd[4] = {};
#pragma unroll
  for (int i = 0; i < 4; ++i) {
    float sv = as2[wv * 64 + i * 16 + r];
    float dv = ad2[wv * 64 + i * 16 + r];
#pragma unroll
    for (int reg = 0; reg < 4; ++reg) {
      ps[reg] += acc[i][reg] * sv;
      pd[reg] += acc[i][reg] * dv;
    }
  }
#pragma unroll
  for (int reg = 0; reg < 4; ++reg)
#pragma unroll
    for (int o = 1; o < 16; o <<= 1) {
      ps[reg] += __shfl_xor(ps[reg], o);
      pd[reg] += __shfl_xor(pd[reg], o);
    }
  if (r == 0) {
#pragma unroll
    for (int reg = 0; reg < 4; ++reg) {
      int row = blockIdx.x * 16 + q * 4 + reg;
      asrc2[row * 4 + wv] = ps[reg];
      adst2[row * 4 + wv] = pd[reg];
    }
  }
  // pack transposed C8 bytes p = r*16 + ntg through LDS, then coalesced store
#pragma unroll
  for (int reg = 0; reg < 4; ++reg) {
    int rowl = q * 4 + reg;
    int w = __builtin_amdgcn_cvt_pk_fp8_f32(acc[0][reg], acc[1][reg], 0, false);
    w = __builtin_amdgcn_cvt_pk_fp8_f32(acc[2][reg], acc[3][reg], w, true);
    sm.ctile[rowl * 64 + r * 4 + wv] = (unsigned)w;
  }
  __syncthreads();
  int row = threadIdx.x >> 4, seg = threadIdx.x & 15;
  uint4 v = *(const uint4*)&sm.ctile[row * 64 + seg * 4];
  *(uint4*)(h8b + ((size_t)(blockIdx.x * 16 + row)) * 256 + (unsigned)seg * 16) = v;
}

// ------- aggregation layer 2 (same core, writes bf16 out rows) ------------------
__global__ void aggregate_kernel(const unsigned char* __restrict__ h8,
                                 const float* __restrict__ asrc,
                                 const float* __restrict__ adst,
                                 const int* __restrict__ cnt,
                                 const unsigned short* __restrict__ csr_src,
                                 const float* __restrict__ bias,
                                 unsigned short* __restrict__ outb) {
  int wave = threadIdx.x >> 6, lane = threadIdx.x & 63;
  int node = blockIdx.x * 4 + wave;              // NN % 4 == 0: always valid
  __shared__ float wtab[4][256];
  __shared__ float red[4][1056];
  float s = agg_node(node, lane, wtab[wave], red[wave], h8, asrc, adst, cnt, csr_src);
  float ov = sigmoidf(s + bias[lane]);
  outb[(size_t)node * 64 + lane] = f2b(ov);     // 128B/wave coalesced
}

// ------- pool partial with FUSED gate MFMA (per-block, own chunk nodes) ----------
__global__ void pool_partial_kernel(const int* __restrict__ goffs,
                                    const unsigned short* __restrict__ out2b,
                                    const unsigned short* __restrict__ Bg,
                                    const float* __restrict__ gb1,
                                    const float* __restrict__ gamma,
                                    const float* __restrict__ beta,
                                    const float* __restrict__ gw2,
                                    const float* __restrict__ gb2,
                                    float* __restrict__ part_acc,
                                    float* __restrict__ part_den) {
  int b = blockIdx.x, j = blockIdx.y;
  int beg = goffs[b], end = goffs[b + 1];
  int chunk = (end - beg + CH - 1) / CH;
  int cb = beg + j * chunk;
  int ce = min(end, cb + chunk);
  int lane = threadIdx.x & 63, wave = threadIdx.x >> 6;
  int q = lane >> 4, r = lane & 15;
  const float s = rsqrtf(1.f + 1e-5f);
  float gb2v = gb2[0];
  float accv = 0.f, den = 0.f;
  for (int n0 = cb + wave * 16; n0 < ce; n0 += 64) {
    // gate MFMA for nodes n0..n0+15
    f32x4 acc[4] = {};
    int row = n0 + r;
    if (row >= NN) row = NN - 1;
    const unsigned short* Arow = out2b + (size_t)row * 64 + q * 8;
#pragma unroll
    for (int kc = 0; kc < 2; ++kc) {
      bf16x8 a = *(const bf16x8*)(Arow + kc * 32);
#pragma unroll
      for (int nt = 0; nt < 4; ++nt) {
        bf16x8 b8 = *(const bf16x8*)&Bg[(((size_t)nt * 2 + kc) * 64 + lane) * 8];
        acc[nt] = __builtin_amdgcn_mfma_f32_16x16x32_bf16(a, b8, acc[nt], 0, 0, 0);
      }
    }
    float sum[4] = {0.f, 0.f, 0.f, 0.f};
#pragma unroll
    for (int nt = 0; nt < 4; ++nt) {
      int col = nt * 16 + r;
      float off = gb1[col] * gamma[col] * s + beta[col];
      float w2 = gw2[col];
#pragma unroll
      for (int reg = 0; reg < 4; ++reg)
        sum[reg] += fmaxf(acc[nt][reg] + off, 0.f) * w2;
    }
#pragma unroll
    for (int reg = 0; reg < 4; ++reg)
#pragma unroll
      for (int o = 1; o < 16; o <<= 1) sum[reg] += __shfl_xor(sum[reg], o);
    float gx[4];
#pragma unroll
    for (int reg = 0; reg < 4; ++reg) {
      int n = n0 + q * 4 + reg;
      gx[reg] = (n < ce) ? __expf(sum[reg] + gb2v) : 0.f;
    }
#pragma unroll
    for (int t = 0; t < 16; ++t) {
      int n = n0 + t;
      if (n >= ce) break;
      float gv = __shfl(gx[t & 3], (t >> 2) << 4);
      accv += gv * b2f(out2b[(size_t)n * 64 + lane]);
      den += gv;  // identical on all lanes
    }
  }
  __shared__ float sacc[4][64];
  __shared__ float sden[4];
  sacc[wave][lane] = accv;
  if (lane == 0) sden[wave] = den;
  __syncthreads();
  if (wave == 0) {
    float a = sacc[0][lane] + sacc[1][lane] + sacc[2][lane] + sacc[3][lane];
    part_acc[((size_t)b * CH + j) * 64 + lane] = a;
    if (lane == 0) part_den[b * CH + j] = sden[0] + sden[1] + sden[2] + sden[3];
  }
}

__global__ void pool_final_kernel(const float* __restrict__ part_acc,
                                  const float* __restrict__ part_den,
                                  const float* __restrict__ lw, const float* __restrict__ lb,
                                  float* __restrict__ out) {
  int b = blockIdx.x, lane = threadIdx.x;  // 64 threads
  float a = 0.f;
#pragma unroll
  for (int j = 0; j < CH; ++j) a += part_acc[((size_t)b * CH + j) * 64 + lane];
  float den = (lane < CH) ? part_den[b * CH + lane] : 0.f;
  den = wred(den);
  den = __shfl(den, 0);
  float p = a / (den + 1e-16f);
  float v = wred(p * lw[lane]);
  if (lane == 0) out[b] = sigmoidf(v + lb[0]);
}

extern "C" void kernel_launch(void* const* d_in, const int* in_sizes, int n_in,
                              void* d_out, int out_size, void* d_ws, size_t ws_size,
                              hipStream_t stream) {
  const float* x    = (const float*)d_in[0];
  const int*   ei   = (const int*)d_in[1];
  const int*   batch= (const int*)d_in[2];
  const float* W1   = (const float*)d_in[4];
  const float* as1  = (const float*)d_in[5];
  const float* ad1  = (const float*)d_in[6];
  const float* b1   = (const float*)d_in[7];
  const float* W2   = (const float*)d_in[8];
  const float* as2  = (const float*)d_in[9];
  const float* ad2  = (const float*)d_in[10];
  const float* b2   = (const float*)d_in[11];
  const float* gw1  = (const float*)d_in[12];
  const float* gb1  = (const float*)d_in[13];
  const float* gamma= (const float*)d_in[14];
  const float* beta = (const float*)d_in[15];
  const float* gw2  = (const float*)d_in[16];
  const float* gb2  = (const float*)d_in[17];
  const float* lw   = (const float*)d_in[18];
  const float* lb   = (const float*)d_in[19];
  float* out = (float*)d_out;

  char* ws = (char*)d_ws;
  size_t off = 0;
  auto alloc = [&](size_t bytes) -> void* {
    void* p = ws + off;
    off = (off + bytes + 255) & ~(size_t)255;
    return p;
  };
  unsigned short* W1b    = (unsigned short*)alloc((size_t)128 * 256 * 2);
  unsigned short* W2b    = (unsigned short*)alloc((size_t)64 * 256 * 2);
  unsigned short* Bg     = (unsigned short*)alloc((size_t)64 * 64 * 2);
  unsigned char*  h8     = (unsigned char*)alloc((size_t)NN * 256);
  unsigned char*  h8b    = (unsigned char*)alloc((size_t)NN * 256);
  unsigned short* out2b  = (unsigned short*)alloc((size_t)NN * 64 * 2);
  float*    asrc    = (float*)alloc((size_t)NN * 4 * 4);
  float*    adst    = (float*)alloc((size_t)NN * 4 * 4);
  float*    asrc2   = (float*)alloc((size_t)NN * 4 * 4);
  float*    adst2   = (float*)alloc((size_t)NN * 4 * 4);
  int*      cnt     = (int*)alloc((size_t)NN * 4);
  unsigned short* csr16 = (unsigned short*)alloc((size_t)NN * SLOTS * 2);
  unsigned* bins    = (unsigned*)alloc((size_t)EBN * NBKT * CAP * 4);
  int*      binCnt  = (int*)alloc((size_t)EBN * NBKT * 4);
  int*      ovf_cnt = (int*)alloc(256);
  unsigned* ovf     = (unsigned*)alloc((size_t)OVFCAP * 4);
  int*      goffs   = (int*)alloc((size_t)(NG + 1) * 4);
  float*    pacc    = (float*)alloc((size_t)NG * CH * 64 * 4);
  float*    pden    = (float*)alloc((size_t)NG * CH * 4);

  // prep: packs + bounds + ovf zero
  prep_kernel<<<209, 256, 0, stream>>>(W1, W2, gw1, gamma, batch,
                                       W1b, W2b, Bg, goffs, ovf_cnt);

  // Layer 1 GEMM + atomic-free bucket histogram (pass A) overlapped in one launch
  gemm1_build_kernel<<<GB + EBN, 256, 0, stream>>>(x, W1b, h8, as1, ad1, asrc, adst,
                                                   ei, bins, binCnt, ovf_cnt, ovf);
  // pass C: finalize csr + cnt per bucket (plain stores, LDS ranks)
  csr_build_kernel<<<NBKT, 1024, 0, stream>>>(bins, binCnt, ovf_cnt, ovf, csr16, cnt);

  // FUSED aggregate1 + gemm2 + attn2 (block = 16 nodes)
  agg1_gemm2_kernel<<<MT, 256, 0, stream>>>(h8, asrc, adst, cnt, csr16, b1,
                                            W2b, as2, ad2, h8b, asrc2, adst2);

  // Layer 2 aggregation
  aggregate_kernel<<<NN / 4, 256, 0, stream>>>(h8b, asrc2, adst2, cnt, csr16, b2, out2b);

  // Global attention pooling (gate MFMA fused into partial)
  pool_partial_kernel<<<dim3(NG, CH), 256, 0, stream>>>(goffs, out2b, Bg, gb1, gamma, beta,
                                                        gw2, gb2, pacc, pden);
  pool_final_kernel<<<NG, 64, 0, stream>>>(pacc, pden, lw, lb, out);
}